// Round 11
// baseline (1841.657 us; speedup 1.0000x reference)
//
#include <hip/hip_runtime.h>
#include <stdint.h>
#include <math.h>

#define N_NODES 1000
#define DIM 256
#define N_EDGES 16000
#define NS 8            // gumbel samples
#define P 2000          // padded sinkhorn size
#define ICB 200         // row chunks for k_build (VALU-bound: max occupancy)
#define RPB (P / ICB)   // rows per build chunk = 10
#define ICF 100         // row chunks for k_fused (HBM-bound: amortize fixed work)
#define RPF (P / ICF)   // rows per fused chunk = 20
#define GR 5            // rows per register-group in k_fused

// ---------------- Threefry-2x32 (exact JAX) ----------------
__host__ __device__ inline void tf2x32(uint32_t k0, uint32_t k1,
                                       uint32_t x0, uint32_t x1,
                                       uint32_t* o0, uint32_t* o1) {
  const uint32_t ks2 = k0 ^ k1 ^ 0x1BD11BDAu;
  uint32_t a = x0 + k0, b = x1 + k1;
#define RL(v, d) (((v) << (d)) | ((v) >> (32 - (d))))
#define RND(r) { a += b; b = RL(b, r); b ^= a; }
  RND(13) RND(15) RND(26) RND(6)
  a += k1;  b += ks2 + 1u;
  RND(17) RND(29) RND(16) RND(24)
  a += ks2; b += k0 + 2u;
  RND(13) RND(15) RND(26) RND(6)
  a += k0;  b += k1 + 3u;
  RND(17) RND(29) RND(16) RND(24)
  a += k1;  b += ks2 + 4u;
  RND(13) RND(15) RND(26) RND(6)
  a += ks2; b += k0 + 5u;
#undef RND
#undef RL
  *o0 = a; *o1 = b;
}

__device__ inline float gumbel_from_idx(uint32_t k0, uint32_t k1, uint32_t idx) {
  uint32_t b0, b1;
  tf2x32(k0, k1, 0u, idx, &b0, &b1);
  uint32_t bits = b0 ^ b1;
  float u = __uint_as_float((bits >> 9) | 0x3f800000u) - 1.0f;
  return -__logf(-__logf(u + 1e-20f) + 1e-20f);
}

// ---------------- block reductions (blockDim==256) ----------------
__device__ inline float blockSum256(float v) {
  __shared__ float sm[4];
  #pragma unroll
  for (int off = 32; off; off >>= 1) v += __shfl_down(v, off, 64);
  if ((threadIdx.x & 63) == 0) sm[threadIdx.x >> 6] = v;
  __syncthreads();
  float r = (sm[0] + sm[1]) + (sm[2] + sm[3]);
  __syncthreads();
  return r;
}
__device__ inline float blockMax256(float v) {
  __shared__ float sm[4];
  #pragma unroll
  for (int off = 32; off; off >>= 1) v = fmaxf(v, __shfl_down(v, off, 64));
  if ((threadIdx.x & 63) == 0) sm[threadIdx.x >> 6] = v;
  __syncthreads();
  float r = fmaxf(fmaxf(sm[0], sm[1]), fmaxf(sm[2], sm[3]));
  __syncthreads();
  return r;
}

// ---------------- CSR build ----------------
__global__ void k_hist(const int* __restrict__ key, int* __restrict__ cnt) {
  int k = blockIdx.x * 256 + threadIdx.x;
  if (k < N_EDGES) atomicAdd(&cnt[key[k]], 1);
}
__global__ void k_scan(const int* __restrict__ cnt, int* __restrict__ start) {
  __shared__ int sm[1024];
  int t = threadIdx.x;
  sm[t] = (t < N_NODES) ? cnt[t] : 0;
  __syncthreads();
  for (int off = 1; off < 1024; off <<= 1) {
    int v = (t >= off) ? sm[t - off] : 0;
    __syncthreads();
    sm[t] += v;
    __syncthreads();
  }
  if (t < N_NODES) start[t + 1] = sm[t];
  if (t == 0) start[0] = 0;
}
__global__ void k_scatter(const int* __restrict__ key, const int* __restrict__ start,
                          int* __restrict__ cursor, int* __restrict__ ids) {
  int k = blockIdx.x * 256 + threadIdx.x;
  if (k < N_EDGES) {
    int c = key[k];
    int slot = start[c] + atomicAdd(&cursor[c], 1);
    ids[slot] = k;
  }
}
__global__ void k_partfill(const int* __restrict__ ids, const int* __restrict__ pv,
                           int* __restrict__ part) {
  int s = blockIdx.x * 256 + threadIdx.x;
  if (s < N_EDGES) part[s] = pv[ids[s]];
}
__global__ void k_packD(const int* __restrict__ startB, const int* __restrict__ partB,
                        int* __restrict__ epackD) {
  int d = blockIdx.x * 256 + threadIdx.x;
  if (d >= N_NODES) return;
  int e0 = startB[d], e1 = startB[d + 1];
  for (int q = e0; q < e1; ++q) epackD[q] = (d << 10) | partB[q];
}

// ---------------- small kernels ----------------
__global__ void k_ones(float* imp) {
  int t = blockIdx.x * 256 + threadIdx.x;
  if (t < 2048) imp[t] = 1.0f;
}

__global__ void k_rowsum(const float* __restrict__ thp, float* __restrict__ imp) {
  int i = blockIdx.x;
  float a = 0.f;
  for (int j = threadIdx.x; j < N_NODES; j += 256) a += thp[(size_t)i * N_NODES + j];
  float s = blockSum256(a);
  if (threadIdx.x == 0) imp[i] = s;
}

__global__ void k_colsum(const float* __restrict__ thp, float* __restrict__ imp) {
  int j = blockIdx.x * 256 + threadIdx.x;
  if (j >= N_NODES) return;
  int r0 = blockIdx.y * 125;
  float a = 0.f;
  for (int i = r0; i < r0 + 125; ++i) a += thp[(size_t)i * N_NODES + j];
  atomicAdd(&imp[1024 + j], a);
}

__global__ void k_scale_b(const float* __restrict__ xs, const float* __restrict__ xt,
                          const float* __restrict__ imp, float* __restrict__ h) {
  int g = blockIdx.y, i = blockIdx.x, d = threadIdx.x;
  const float* x = g ? xt : xs;
  h[(size_t)g * 256000 + i * DIM + d] = x[i * DIM + d] * imp[g * 1024 + i];
}

__global__ void k_agg_b(const float* __restrict__ h, const int* __restrict__ start,
                        const int* __restrict__ part, float* __restrict__ agg) {
  int g = blockIdx.y, i = blockIdx.x, d = threadIdx.x;
  const int* st = start + g * 1008;
  const int* pt = part + g * 16000;
  const float* hh = h + (size_t)g * 256000;
  int e0 = st[i], e1 = st[i + 1];
  float a = 0.f;
  for (int q = e0; q < e1; ++q) a += hh[(size_t)pt[q] * DIM + d];
  agg[(size_t)g * 256000 + i * DIM + d] = a;
}

__global__ void __launch_bounds__(256) k_lin_b(const float* __restrict__ h_,
    const float* __restrict__ agg_, const float* __restrict__ Wm,
    const float* __restrict__ bias, float* __restrict__ out_, int relu) {
  __shared__ float As[16][64];
  __shared__ float Ws[64][64];
  int g = blockIdx.z;
  const float* h   = h_   + (size_t)g * 256000;
  const float* agg = agg_ + (size_t)g * 256000;
  float* out       = out_ + (size_t)g * 256000;
  int tx = threadIdx.x & 63;
  int ty = threadIdx.x >> 6;
  int row0 = blockIdx.x * 16;
  int col0 = blockIdx.y * 64;
  float acc[4] = {0.f, 0.f, 0.f, 0.f};
  for (int kc = 0; kc < DIM; kc += 64) {
    for (int t = threadIdx.x; t < 16 * 64; t += 256) {
      int r = t >> 6, c = t & 63;
      int gr = row0 + r;
      As[r][c] = (gr < N_NODES) ? (h[gr * DIM + kc + c] + agg[gr * DIM + kc + c]) : 0.f;
    }
    for (int t = threadIdx.x; t < 64 * 64; t += 256) {
      int r = t >> 6, c = t & 63;
      Ws[r][c] = Wm[(kc + r) * DIM + col0 + c];
    }
    __syncthreads();
    #pragma unroll 8
    for (int kk = 0; kk < 64; ++kk) {
      float w = Ws[kk][tx];
      acc[0] += As[ty][kk] * w;
      acc[1] += As[ty + 4][kk] * w;
      acc[2] += As[ty + 8][kk] * w;
      acc[3] += As[ty + 12][kk] * w;
    }
    __syncthreads();
  }
  int col = col0 + tx;
  float bv = bias[col];
  #pragma unroll
  for (int r = 0; r < 4; ++r) {
    int gr = row0 + ty + r * 4;
    if (gr < N_NODES) {
      float vv = acc[r] + bv;
      if (relu) vv = fmaxf(vv, 0.f);
      out[gr * DIM + col] = vv;
    }
  }
}

__global__ void k_norm_b(const float* __restrict__ h, float* __restrict__ out) {
  int g = blockIdx.y, i = blockIdx.x;
  float x = h[(size_t)g * 256000 + i * DIM + threadIdx.x];
  float ss = blockSum256(x * x);
  float nrm = sqrtf(ss);
  out[(size_t)g * 256000 + i * DIM + threadIdx.x] = x / nrm;
}

__global__ void __launch_bounds__(256) k_gemm50(const float* __restrict__ A,
    const float* __restrict__ B, float* __restrict__ C) {
  __shared__ float As[64][33];
  __shared__ float Bs[64][33];
  int tr = threadIdx.x >> 4;
  int tc = threadIdx.x & 15;
  int i0 = blockIdx.x * 64, j0 = blockIdx.y * 64;
  float acc[4][4] = {};
  for (int kc = 0; kc < DIM; kc += 32) {
    for (int t = threadIdx.x; t < 64 * 32; t += 256) {
      int r = t >> 5, c = t & 31;
      int gi = i0 + r; As[r][c] = (gi < N_NODES) ? A[gi * DIM + kc + c] : 0.f;
      int gj = j0 + r; Bs[r][c] = (gj < N_NODES) ? B[gj * DIM + kc + c] : 0.f;
    }
    __syncthreads();
    for (int kk = 0; kk < 32; ++kk) {
      float a[4], b[4];
      #pragma unroll
      for (int q = 0; q < 4; ++q) a[q] = As[tr * 4 + q][kk];
      #pragma unroll
      for (int q = 0; q < 4; ++q) b[q] = Bs[tc * 4 + q][kk];
      #pragma unroll
      for (int r = 0; r < 4; ++r)
        #pragma unroll
        for (int c = 0; c < 4; ++c) acc[r][c] += a[r] * b[c];
    }
    __syncthreads();
  }
  for (int r = 0; r < 4; ++r) {
    int gi = i0 + tr * 4 + r;
    if (gi >= N_NODES) continue;
    for (int c = 0; c < 4; ++c) {
      int gj = j0 + tc * 4 + c;
      if (gj < N_NODES) C[(size_t)gi * N_NODES + gj] = 50.0f * acc[r][c];
    }
  }
}

// build: base = (pad(la)+g)*10; u1 = rowLSE (max-subtracted); v1-partials
// grid (ICB, NS): 1600 blocks for occupancy (VALU-bound threefry chain)
__global__ void __launch_bounds__(256) k_build(const float* __restrict__ la,
    float* __restrict__ base, float* __restrict__ u, float* __restrict__ ps,
    uint32_t k0, uint32_t k1) {
  int ic = blockIdx.x, s = blockIdx.y;
  int t = threadIdx.x;
  int j0 = t * 8;
  bool act = (j0 < P);
  float acc[8] = {0.f,0.f,0.f,0.f,0.f,0.f,0.f,0.f};
  for (int r = 0; r < RPB; ++r) {
    int i = ic * RPB + r;
    float bv[8];
    float lmax = -INFINITY;
    if (act) {
      uint32_t idxbase = (uint32_t)((s * P + i) * P + j0);
      #pragma unroll
      for (int q = 0; q < 8; ++q) {
        int j = j0 + q;
        float g = gumbel_from_idx(k0, k1, idxbase + (uint32_t)q);
        float lav = (i < N_NODES && j < N_NODES) ? la[(size_t)i * N_NODES + j] : 0.0f;
        bv[q] = (lav + g) * 10.0f;
        lmax = fmaxf(lmax, bv[q]);
      }
      float4* p = (float4*)(base + ((size_t)s * P + i) * P + j0);
      p[0] = make_float4(bv[0], bv[1], bv[2], bv[3]);
      p[1] = make_float4(bv[4], bv[5], bv[6], bv[7]);
    }
    float M = blockMax256(lmax);
    float e[8];
    float ls = 0.f;
    if (act) {
      #pragma unroll
      for (int q = 0; q < 8; ++q) { e[q] = __expf(bv[q] - M); ls += e[q]; }
    }
    float S = blockSum256(ls);
    if (t == 0) u[s * P + i] = M + __logf(S);
    if (act) {
      float rs = 1.0f / S;
      #pragma unroll
      for (int q = 0; q < 8; ++q) acc[q] += e[q] * rs;
    }
  }
  if (act) {
    float* pp = ps + ((size_t)(s * ICB + ic)) * 2048 + j0;
    ((float4*)pp)[0] = make_float4(acc[0], acc[1], acc[2], acc[3]);
    ((float4*)pp)[1] = make_float4(acc[4], acc[5], acc[6], acc[7]);
  }
}

// fused sinkhorn pass, register-group structure; grid (ICF, NS)
// per 5-row group: read+exp into regs, wave-reduce (no barrier),
// 2 barriers finalize S, then acc += e*(1/S) from registers.
__global__ void __launch_bounds__(256) k_fused(const float* __restrict__ base,
    const float* __restrict__ v, float* __restrict__ u, float* __restrict__ ps) {
  int ic = blockIdx.x, s = blockIdx.y;
  int t = threadIdx.x;
  int lane = t & 63, wave = t >> 6;
  int j0 = t * 8;
  bool act = (j0 < P);
  __shared__ float pr[GR][4];
  __shared__ float Sr[GR];
  float vr[8];
  if (act) {
    float4 v0 = *(const float4*)(v + s * P + j0);
    float4 v1 = *(const float4*)(v + s * P + j0 + 4);
    vr[0]=v0.x; vr[1]=v0.y; vr[2]=v0.z; vr[3]=v0.w;
    vr[4]=v1.x; vr[5]=v1.y; vr[6]=v1.z; vr[7]=v1.w;
  }
  float acc[8] = {0.f,0.f,0.f,0.f,0.f,0.f,0.f,0.f};
  for (int g = 0; g < RPF / GR; ++g) {
    float e[GR][8];
    #pragma unroll
    for (int r = 0; r < GR; ++r) {
      int i = ic * RPF + g * GR + r;
      float uo = u[s * P + i];
      float ls = 0.f;
      if (act) {
        const float* brow = base + ((size_t)s * P + i) * P + j0;
        float4 b0 = *(const float4*)brow;
        float4 b1 = *(const float4*)(brow + 4);
        e[r][0] = __expf(b0.x - uo - vr[0]);
        e[r][1] = __expf(b0.y - uo - vr[1]);
        e[r][2] = __expf(b0.z - uo - vr[2]);
        e[r][3] = __expf(b0.w - uo - vr[3]);
        e[r][4] = __expf(b1.x - uo - vr[4]);
        e[r][5] = __expf(b1.y - uo - vr[5]);
        e[r][6] = __expf(b1.z - uo - vr[6]);
        e[r][7] = __expf(b1.w - uo - vr[7]);
        #pragma unroll
        for (int q = 0; q < 8; ++q) ls += e[r][q];
      }
      #pragma unroll
      for (int off = 32; off; off >>= 1) ls += __shfl_down(ls, off, 64);
      if (lane == 0) pr[r][wave] = ls;
    }
    __syncthreads();
    if (t < GR) {
      float S = (pr[t][0] + pr[t][1]) + (pr[t][2] + pr[t][3]);
      Sr[t] = S;
      u[s * P + ic * RPF + g * GR + t] += __logf(S);
    }
    __syncthreads();
    if (act) {
      #pragma unroll
      for (int r = 0; r < GR; ++r) {
        float rs = 1.0f / Sr[r];
        #pragma unroll
        for (int q = 0; q < 8; ++q) acc[q] += e[r][q] * rs;
      }
    }
  }
  if (act) {
    float* pp = ps + ((size_t)(s * ICF + ic)) * 2048 + j0;
    ((float4*)pp)[0] = make_float4(acc[0], acc[1], acc[2], acc[3]);
    ((float4*)pp)[1] = make_float4(acc[4], acc[5], acc[6], acc[7]);
  }
}

// v_new_j = v_old_j + log(sum_c ps[s][c][j]); NCH compile-time so the chunk
// loop fully unrolls (runtime bound serialized the loads -> +400us in R10)
template<int NCH>
__global__ void k_combine(const float* __restrict__ ps, float* __restrict__ v) {
  int j = blockIdx.x * 256 + threadIdx.x;
  int s = blockIdx.y;
  if (j >= P) return;
  float S = 0.f;
  #pragma unroll
  for (int c = 0; c < NCH; ++c) S += ps[((size_t)(s * NCH + c)) * 2048 + j];
  v[s * P + j] += __logf(S);
}

// theta[s,i,j] = exp(base - u - v) for all 8 samples; fused mean -> thp
// grid (1000, 2) x 128: blockIdx.y selects column half for occupancy
__global__ void __launch_bounds__(128) k_theta_mean(const float* __restrict__ base,
    const float* __restrict__ u, const float* __restrict__ v,
    float* __restrict__ th, float* __restrict__ thp) {
  int i = blockIdx.x, t = threadIdx.x;
  if (t >= 125) return;
  int j0 = blockIdx.y * 500 + t * 4;
  float4 acc = make_float4(0.f, 0.f, 0.f, 0.f);
  #pragma unroll
  for (int s = 0; s < NS; ++s) {
    float ui = u[s * P + i];
    float4 b = *(const float4*)(base + ((size_t)s * P + i) * P + j0);
    float4 vv = *(const float4*)(v + s * P + j0);
    float4 t4;
    t4.x = __expf(b.x - ui - vv.x);
    t4.y = __expf(b.y - ui - vv.y);
    t4.z = __expf(b.z - ui - vv.z);
    t4.w = __expf(b.w - ui - vv.w);
    *(float4*)(th + ((size_t)s * N_NODES + i) * N_NODES + j0) = t4;
    acc.x += t4.x; acc.y += t4.y; acc.z += t4.z; acc.w += t4.w;
  }
  acc.x *= 0.125f; acc.y *= 0.125f; acc.z *= 0.125f; acc.w *= 0.125f;
  *(float4*)(thp + (size_t)i * N_NODES + j0) = acc;
}

// fused reward, XCD-affinity: s = blockIdx.x & 7 so all blocks touching
// theta[s] (4 MB = one XCD L2) land on the same XCD (id%8 round-robin).
__global__ void __launch_bounds__(256) k_reward(const float* __restrict__ th,
    const int* __restrict__ startA, const int* __restrict__ partA,
    const int* __restrict__ epackD, float* __restrict__ matched) {
  __shared__ float yrow[N_NODES];
  __shared__ float xrow[N_NODES];
  int s = blockIdx.x & 7, b = blockIdx.x >> 3;
  int t = threadIdx.x;
  const float* xr = th + ((size_t)s * N_NODES + b) * N_NODES;
  float4 y4 = make_float4(0.f, 0.f, 0.f, 0.f);
  if (t < 250) {
    ((float4*)xrow)[t] = ((const float4*)xr)[t];
    int e0 = startA[b], e1 = startA[b + 1];
    for (int q = e0; q < e1; ++q) {
      float4 vv = ((const float4*)(th + ((size_t)s * N_NODES + partA[q]) * N_NODES))[t];
      y4.x += vv.x; y4.y += vv.y; y4.z += vv.z; y4.w += vv.w;
    }
    ((float4*)yrow)[t] = y4;
  }
  __syncthreads();
  float acc = 0.f;
  for (int m = t; m < N_EDGES; m += 256) {
    int pk = epackD[m];
    acc += yrow[pk >> 10] * xrow[pk & 1023];
  }
  float ssum = blockSum256(acc);
  if (t == 0) atomicAdd(matched + s, ssum);
}

__global__ void k_fin0(const float* __restrict__ matched, float* __restrict__ scal) {
  if (threadIdx.x == 0) {
    float accm = 0.f;
    for (int s = 0; s < NS; ++s) {
      float m = matched[s];
      float rv = m + (-1.0f) * ((16000.0f - m) + (16000.0f - m));
      accm += rv;
    }
    scal[0] = (accm / 8.0f) / 16000.0f;
  }
}

__global__ void k_fin1(const float* __restrict__ matched, float* __restrict__ scal,
                       float* __restrict__ out) {
  if (threadIdx.x == 0) {
    float accm = 0.f;
    for (int s = 0; s < NS; ++s) {
      float m = matched[s];
      float rv = m + (-1.0f) * ((16000.0f - m) + (16000.0f - m));
      accm += rv;
    }
    float r1 = (accm / 8.0f) / 16000.0f;
    float r0 = scal[0];
    int improved = (r1 > r0) ? 1 : 0;
    scal[1] = r1;
    scal[2] = (float)improved;
    float loss = -r0 - (improved ? r1 : 0.f);
    float cnt = improved ? 2.0f : 1.0f;
    out[(size_t)P * P] = loss / cnt;
  }
}

__global__ void k_out_sel(const float* __restrict__ laA, const float* __restrict__ laB,
                          const float* __restrict__ scal, float* __restrict__ out) {
  int q = blockIdx.x * 256 + threadIdx.x;
  if (q >= P * P / 4) return;
  const float* la = (scal[2] != 0.0f) ? laB : laA;
  int row = q / (P / 4);
  int jc = (q % (P / 4)) * 4;
  float4 vv = make_float4(0.f, 0.f, 0.f, 0.f);
  if (row < N_NODES && jc < N_NODES)
    vv = *(const float4*)(la + (size_t)row * N_NODES + jc);
  *(float4*)(out + (size_t)row * P + jc) = vv;
}

// ---------------- launch ----------------
extern "C" void kernel_launch(void* const* d_in, const int* in_sizes, int n_in,
                              void* d_out, int out_size, void* d_ws, size_t ws_size,
                              hipStream_t stream) {
  (void)in_sizes; (void)n_in; (void)out_size; (void)ws_size;
  const float* x_s = (const float*)d_in[0];
  const int*   e_s = (const int*)d_in[1];
  const float* x_t = (const float*)d_in[2];
  const int*   e_t = (const int*)d_in[3];
  const float* W1  = (const float*)d_in[4];
  const float* b1  = (const float*)d_in[5];
  const float* W2  = (const float*)d_in[6];
  const float* b2  = (const float*)d_in[7];
  float* out = (float*)d_out;

  float* ws    = (float*)d_ws;
  float* base  = ws;                       // 32,000,000
  float* theta = base + 32000000;          //  8,000,000
  float* laA   = theta + 8000000;          //  1,000,000
  float* laB   = laA + 1000000;            //  1,000,000
  float* thp   = laB + 1000000;            //  1,000,000
  float* h0    = thp + 1000000;            //    512,000
  float* agg   = h0 + 512000;
  float* h1    = agg + 512000;
  float* h2    = h1 + 512000;
  float* hn    = h2 + 512000;
  float* uarr  = hn + 512000;              //     16,000
  float* varr  = uarr + 16000;             //     16,000
  float* ps    = varr + 16000;             //  3,276,800 (ICB*NS*2048 max)
  float* imp   = ps + 3276800;             //      2,048
  float* matched = imp + 2048;             //         16
  float* scal  = matched + 16;             //         16
  int* ibase  = (int*)(scal + 16);
  int* cnt    = ibase;                     // 1,024
  int* cursor = cnt + 1024;                // 1,024
  int* ids    = cursor + 1024;             // 16,000
  int* startA = ids + 16000;               // 1,008
  int* startB = startA + 1008;             // 1,008
  int* partA  = startB + 1008;             // 16,000
  int* partB  = partA + 16000;             // 16,000
  int* epackD = partB + 16000;             // 16,000

  const int* keys[2]  = { e_s + N_EDGES, e_t + N_EDGES };
  const int* parts[2] = { e_s,           e_t           };
  int* outs_s[2] = { startA, startB };
  int* outs_p[2] = { partA,  partB  };
  for (int r = 0; r < 2; ++r) {
    hipMemsetAsync(cnt, 0, 2048 * sizeof(int), stream);
    k_hist<<<63, 256, 0, stream>>>(keys[r], cnt);
    k_scan<<<1, 1024, 0, stream>>>(cnt, outs_s[r]);
    k_scatter<<<63, 256, 0, stream>>>(keys[r], outs_s[r], cursor, ids);
    k_partfill<<<63, 256, 0, stream>>>(ids, parts[r], outs_p[r]);
  }
  k_packD<<<4, 256, 0, stream>>>(startB, partB, epackD);

  uint32_t k0 = 0u, k1 = 42u;
  uint32_t sub[2][2];
  for (int it = 0; it < 2; ++it) {
    uint32_t nk0, nk1, s0, s1;
    tf2x32(k0, k1, 0u, 0u, &nk0, &nk1);
    tf2x32(k0, k1, 0u, 1u, &s0, &s1);
    sub[it][0] = s0; sub[it][1] = s1;
    k0 = nk0; k1 = nk1;
  }

  for (int it = 0; it < 2; ++it) {
    if (it == 0) {
      k_ones<<<8, 256, 0, stream>>>(imp);
    } else {
      k_rowsum<<<N_NODES, 256, 0, stream>>>(thp, imp);
      hipMemsetAsync(imp + 1024, 0, 1024 * sizeof(float), stream);
      k_colsum<<<dim3(4, 8), 256, 0, stream>>>(thp, imp);
    }
    k_scale_b<<<dim3(N_NODES, 2), 256, 0, stream>>>(x_s, x_t, imp, h0);
    k_agg_b<<<dim3(N_NODES, 2), 256, 0, stream>>>(h0, startA, partA, agg);
    k_lin_b<<<dim3(63, 4, 2), 256, 0, stream>>>(h0, agg, W1, b1, h1, 1);
    k_agg_b<<<dim3(N_NODES, 2), 256, 0, stream>>>(h1, startA, partA, agg);
    k_lin_b<<<dim3(63, 4, 2), 256, 0, stream>>>(h1, agg, W2, b2, h2, 0);
    k_norm_b<<<dim3(N_NODES, 2), 256, 0, stream>>>(h2, hn);
    float* la = it ? laB : laA;
    k_gemm50<<<dim3(16, 16), 256, 0, stream>>>(hn, hn + 256000, la);

    // sinkhorn: build(ICB) + 9 fused(ICF) passes; combine compile-time NCH
    hipMemsetAsync(varr, 0, NS * P * sizeof(float), stream);
    k_build<<<dim3(ICB, NS), 256, 0, stream>>>(la, base, uarr, ps,
                                               sub[it][0], sub[it][1]);
    k_combine<ICB><<<dim3(8, NS), 256, 0, stream>>>(ps, varr);
    for (int k = 0; k < 9; ++k) {
      k_fused<<<dim3(ICF, NS), 256, 0, stream>>>(base, varr, uarr, ps);
      k_combine<ICF><<<dim3(8, NS), 256, 0, stream>>>(ps, varr);
    }

    k_theta_mean<<<dim3(N_NODES, 2), 128, 0, stream>>>(base, uarr, varr, theta, thp);
    hipMemsetAsync(matched, 0, NS * 4, stream);
    k_reward<<<8000, 256, 0, stream>>>(theta, startA, partA, epackD, matched);
    if (it == 0) k_fin0<<<1, 64, 0, stream>>>(matched, scal);
    else         k_fin1<<<1, 64, 0, stream>>>(matched, scal, out);
  }
  k_out_sel<<<3907, 256, 0, stream>>>(laA, laB, scal, out);
}

// Round 12
// 1404.856 us; speedup vs baseline: 1.3109x; 1.3109x over previous
//
#include <hip/hip_runtime.h>
#include <stdint.h>
#include <math.h>

#define N_NODES 1000
#define DIM 256
#define N_EDGES 16000
#define NS 8            // gumbel samples
#define P 2000          // padded sinkhorn size
#define IC2 100         // row chunks for k_fused (R8 measured config)
#define RPC (P / IC2)   // rows per fused chunk = 20
#define ICB 200         // row chunks for k_build only (measured: 160->135us)
#define RPB (P / ICB)   // rows per build chunk = 10
#define GR 5            // rows per register-group in k_fused

// ---------------- Threefry-2x32 (exact JAX) ----------------
__host__ __device__ inline void tf2x32(uint32_t k0, uint32_t k1,
                                       uint32_t x0, uint32_t x1,
                                       uint32_t* o0, uint32_t* o1) {
  const uint32_t ks2 = k0 ^ k1 ^ 0x1BD11BDAu;
  uint32_t a = x0 + k0, b = x1 + k1;
#define RL(v, d) (((v) << (d)) | ((v) >> (32 - (d))))
#define RND(r) { a += b; b = RL(b, r); b ^= a; }
  RND(13) RND(15) RND(26) RND(6)
  a += k1;  b += ks2 + 1u;
  RND(17) RND(29) RND(16) RND(24)
  a += ks2; b += k0 + 2u;
  RND(13) RND(15) RND(26) RND(6)
  a += k0;  b += k1 + 3u;
  RND(17) RND(29) RND(16) RND(24)
  a += k1;  b += ks2 + 4u;
  RND(13) RND(15) RND(26) RND(6)
  a += ks2; b += k0 + 5u;
#undef RND
#undef RL
  *o0 = a; *o1 = b;
}

__device__ inline float gumbel_from_idx(uint32_t k0, uint32_t k1, uint32_t idx) {
  uint32_t b0, b1;
  tf2x32(k0, k1, 0u, idx, &b0, &b1);
  uint32_t bits = b0 ^ b1;
  float u = __uint_as_float((bits >> 9) | 0x3f800000u) - 1.0f;
  return -__logf(-__logf(u + 1e-20f) + 1e-20f);
}

// ---------------- block reductions (blockDim==256) ----------------
__device__ inline float blockSum256(float v) {
  __shared__ float sm[4];
  #pragma unroll
  for (int off = 32; off; off >>= 1) v += __shfl_down(v, off, 64);
  if ((threadIdx.x & 63) == 0) sm[threadIdx.x >> 6] = v;
  __syncthreads();
  float r = (sm[0] + sm[1]) + (sm[2] + sm[3]);
  __syncthreads();
  return r;
}
__device__ inline float blockMax256(float v) {
  __shared__ float sm[4];
  #pragma unroll
  for (int off = 32; off; off >>= 1) v = fmaxf(v, __shfl_down(v, off, 64));
  if ((threadIdx.x & 63) == 0) sm[threadIdx.x >> 6] = v;
  __syncthreads();
  float r = fmaxf(fmaxf(sm[0], sm[1]), fmaxf(sm[2], sm[3]));
  __syncthreads();
  return r;
}

// ---------------- CSR build ----------------
__global__ void k_hist(const int* __restrict__ key, int* __restrict__ cnt) {
  int k = blockIdx.x * 256 + threadIdx.x;
  if (k < N_EDGES) atomicAdd(&cnt[key[k]], 1);
}
__global__ void k_scan(const int* __restrict__ cnt, int* __restrict__ start) {
  __shared__ int sm[1024];
  int t = threadIdx.x;
  sm[t] = (t < N_NODES) ? cnt[t] : 0;
  __syncthreads();
  for (int off = 1; off < 1024; off <<= 1) {
    int v = (t >= off) ? sm[t - off] : 0;
    __syncthreads();
    sm[t] += v;
    __syncthreads();
  }
  if (t < N_NODES) start[t + 1] = sm[t];
  if (t == 0) start[0] = 0;
}
__global__ void k_scatter(const int* __restrict__ key, const int* __restrict__ start,
                          int* __restrict__ cursor, int* __restrict__ ids) {
  int k = blockIdx.x * 256 + threadIdx.x;
  if (k < N_EDGES) {
    int c = key[k];
    int slot = start[c] + atomicAdd(&cursor[c], 1);
    ids[slot] = k;
  }
}
__global__ void k_partfill(const int* __restrict__ ids, const int* __restrict__ pv,
                           int* __restrict__ part) {
  int s = blockIdx.x * 256 + threadIdx.x;
  if (s < N_EDGES) part[s] = pv[ids[s]];
}
__global__ void k_packD(const int* __restrict__ startB, const int* __restrict__ partB,
                        int* __restrict__ epackD) {
  int d = blockIdx.x * 256 + threadIdx.x;
  if (d >= N_NODES) return;
  int e0 = startB[d], e1 = startB[d + 1];
  for (int q = e0; q < e1; ++q) epackD[q] = (d << 10) | partB[q];
}

// ---------------- small kernels ----------------
__global__ void k_ones(float* imp) {
  int t = blockIdx.x * 256 + threadIdx.x;
  if (t < 2048) imp[t] = 1.0f;
}

__global__ void k_rowsum(const float* __restrict__ thp, float* __restrict__ imp) {
  int i = blockIdx.x;
  float a = 0.f;
  for (int j = threadIdx.x; j < N_NODES; j += 256) a += thp[(size_t)i * N_NODES + j];
  float s = blockSum256(a);
  if (threadIdx.x == 0) imp[i] = s;
}

__global__ void k_colsum(const float* __restrict__ thp, float* __restrict__ imp) {
  int j = blockIdx.x * 256 + threadIdx.x;
  if (j >= N_NODES) return;
  int r0 = blockIdx.y * 125;
  float a = 0.f;
  for (int i = r0; i < r0 + 125; ++i) a += thp[(size_t)i * N_NODES + j];
  atomicAdd(&imp[1024 + j], a);
}

__global__ void k_scale_b(const float* __restrict__ xs, const float* __restrict__ xt,
                          const float* __restrict__ imp, float* __restrict__ h) {
  int g = blockIdx.y, i = blockIdx.x, d = threadIdx.x;
  const float* x = g ? xt : xs;
  h[(size_t)g * 256000 + i * DIM + d] = x[i * DIM + d] * imp[g * 1024 + i];
}

__global__ void k_agg_b(const float* __restrict__ h, const int* __restrict__ start,
                        const int* __restrict__ part, float* __restrict__ agg) {
  int g = blockIdx.y, i = blockIdx.x, d = threadIdx.x;
  const int* st = start + g * 1008;
  const int* pt = part + g * 16000;
  const float* hh = h + (size_t)g * 256000;
  int e0 = st[i], e1 = st[i + 1];
  float a = 0.f;
  for (int q = e0; q < e1; ++q) a += hh[(size_t)pt[q] * DIM + d];
  agg[(size_t)g * 256000 + i * DIM + d] = a;
}

__global__ void __launch_bounds__(256) k_lin_b(const float* __restrict__ h_,
    const float* __restrict__ agg_, const float* __restrict__ Wm,
    const float* __restrict__ bias, float* __restrict__ out_, int relu) {
  __shared__ float As[16][64];
  __shared__ float Ws[64][64];
  int g = blockIdx.z;
  const float* h   = h_   + (size_t)g * 256000;
  const float* agg = agg_ + (size_t)g * 256000;
  float* out       = out_ + (size_t)g * 256000;
  int tx = threadIdx.x & 63;
  int ty = threadIdx.x >> 6;
  int row0 = blockIdx.x * 16;
  int col0 = blockIdx.y * 64;
  float acc[4] = {0.f, 0.f, 0.f, 0.f};
  for (int kc = 0; kc < DIM; kc += 64) {
    for (int t = threadIdx.x; t < 16 * 64; t += 256) {
      int r = t >> 6, c = t & 63;
      int gr = row0 + r;
      As[r][c] = (gr < N_NODES) ? (h[gr * DIM + kc + c] + agg[gr * DIM + kc + c]) : 0.f;
    }
    for (int t = threadIdx.x; t < 64 * 64; t += 256) {
      int r = t >> 6, c = t & 63;
      Ws[r][c] = Wm[(kc + r) * DIM + col0 + c];
    }
    __syncthreads();
    #pragma unroll 8
    for (int kk = 0; kk < 64; ++kk) {
      float w = Ws[kk][tx];
      acc[0] += As[ty][kk] * w;
      acc[1] += As[ty + 4][kk] * w;
      acc[2] += As[ty + 8][kk] * w;
      acc[3] += As[ty + 12][kk] * w;
    }
    __syncthreads();
  }
  int col = col0 + tx;
  float bv = bias[col];
  #pragma unroll
  for (int r = 0; r < 4; ++r) {
    int gr = row0 + ty + r * 4;
    if (gr < N_NODES) {
      float vv = acc[r] + bv;
      if (relu) vv = fmaxf(vv, 0.f);
      out[gr * DIM + col] = vv;
    }
  }
}

__global__ void k_norm_b(const float* __restrict__ h, float* __restrict__ out) {
  int g = blockIdx.y, i = blockIdx.x;
  float x = h[(size_t)g * 256000 + i * DIM + threadIdx.x];
  float ss = blockSum256(x * x);
  float nrm = sqrtf(ss);
  out[(size_t)g * 256000 + i * DIM + threadIdx.x] = x / nrm;
}

__global__ void __launch_bounds__(256) k_gemm50(const float* __restrict__ A,
    const float* __restrict__ B, float* __restrict__ C) {
  __shared__ float As[64][33];
  __shared__ float Bs[64][33];
  int tr = threadIdx.x >> 4;
  int tc = threadIdx.x & 15;
  int i0 = blockIdx.x * 64, j0 = blockIdx.y * 64;
  float acc[4][4] = {};
  for (int kc = 0; kc < DIM; kc += 32) {
    for (int t = threadIdx.x; t < 64 * 32; t += 256) {
      int r = t >> 5, c = t & 31;
      int gi = i0 + r; As[r][c] = (gi < N_NODES) ? A[gi * DIM + kc + c] : 0.f;
      int gj = j0 + r; Bs[r][c] = (gj < N_NODES) ? B[gj * DIM + kc + c] : 0.f;
    }
    __syncthreads();
    for (int kk = 0; kk < 32; ++kk) {
      float a[4], b[4];
      #pragma unroll
      for (int q = 0; q < 4; ++q) a[q] = As[tr * 4 + q][kk];
      #pragma unroll
      for (int q = 0; q < 4; ++q) b[q] = Bs[tc * 4 + q][kk];
      #pragma unroll
      for (int r = 0; r < 4; ++r)
        #pragma unroll
        for (int c = 0; c < 4; ++c) acc[r][c] += a[r] * b[c];
    }
    __syncthreads();
  }
  for (int r = 0; r < 4; ++r) {
    int gi = i0 + tr * 4 + r;
    if (gi >= N_NODES) continue;
    for (int c = 0; c < 4; ++c) {
      int gj = j0 + tc * 4 + c;
      if (gj < N_NODES) C[(size_t)gi * N_NODES + gj] = 50.0f * acc[r][c];
    }
  }
}

// build: base = (pad(la)+g)*10; u1 = rowLSE (max-subtracted); v1-partials
// grid (ICB, NS) = 1600 blocks: VALU-bound threefry needs occupancy
__global__ void __launch_bounds__(256) k_build(const float* __restrict__ la,
    float* __restrict__ base, float* __restrict__ u, float* __restrict__ ps,
    uint32_t k0, uint32_t k1) {
  int ic = blockIdx.x, s = blockIdx.y;
  int t = threadIdx.x;
  int j0 = t * 8;
  bool act = (j0 < P);
  float acc[8] = {0.f,0.f,0.f,0.f,0.f,0.f,0.f,0.f};
  for (int r = 0; r < RPB; ++r) {
    int i = ic * RPB + r;
    float bv[8];
    float lmax = -INFINITY;
    if (act) {
      uint32_t idxbase = (uint32_t)((s * P + i) * P + j0);
      #pragma unroll
      for (int q = 0; q < 8; ++q) {
        int j = j0 + q;
        float g = gumbel_from_idx(k0, k1, idxbase + (uint32_t)q);
        float lav = (i < N_NODES && j < N_NODES) ? la[(size_t)i * N_NODES + j] : 0.0f;
        bv[q] = (lav + g) * 10.0f;
        lmax = fmaxf(lmax, bv[q]);
      }
      float4* p = (float4*)(base + ((size_t)s * P + i) * P + j0);
      p[0] = make_float4(bv[0], bv[1], bv[2], bv[3]);
      p[1] = make_float4(bv[4], bv[5], bv[6], bv[7]);
    }
    float M = blockMax256(lmax);
    float e[8];
    float ls = 0.f;
    if (act) {
      #pragma unroll
      for (int q = 0; q < 8; ++q) { e[q] = __expf(bv[q] - M); ls += e[q]; }
    }
    float S = blockSum256(ls);
    if (t == 0) u[s * P + i] = M + __logf(S);
    if (act) {
      float rs = 1.0f / S;
      #pragma unroll
      for (int q = 0; q < 8; ++q) acc[q] += e[q] * rs;
    }
  }
  if (act) {
    float* pp = ps + ((size_t)(s * ICB + ic)) * 2048 + j0;
    ((float4*)pp)[0] = make_float4(acc[0], acc[1], acc[2], acc[3]);
    ((float4*)pp)[1] = make_float4(acc[4], acc[5], acc[6], acc[7]);
  }
}

// fused sinkhorn pass (R8 measured config): grid (IC2, NS), RPC=20 rows.
// per 5-row group: read+exp into regs, wave-reduce (no barrier),
// 2 barriers finalize S, then acc += e*(1/S) from registers.
__global__ void __launch_bounds__(256) k_fused(const float* __restrict__ base,
    const float* __restrict__ v, float* __restrict__ u, float* __restrict__ ps) {
  int ic = blockIdx.x, s = blockIdx.y;
  int t = threadIdx.x;
  int lane = t & 63, wave = t >> 6;
  int j0 = t * 8;
  bool act = (j0 < P);
  __shared__ float pr[GR][4];
  __shared__ float Sr[GR];
  float vr[8];
  if (act) {
    float4 v0 = *(const float4*)(v + s * P + j0);
    float4 v1 = *(const float4*)(v + s * P + j0 + 4);
    vr[0]=v0.x; vr[1]=v0.y; vr[2]=v0.z; vr[3]=v0.w;
    vr[4]=v1.x; vr[5]=v1.y; vr[6]=v1.z; vr[7]=v1.w;
  }
  float acc[8] = {0.f,0.f,0.f,0.f,0.f,0.f,0.f,0.f};
  for (int g = 0; g < RPC / GR; ++g) {
    float e[GR][8];
    #pragma unroll
    for (int r = 0; r < GR; ++r) {
      int i = ic * RPC + g * GR + r;
      float uo = u[s * P + i];
      float ls = 0.f;
      if (act) {
        const float* brow = base + ((size_t)s * P + i) * P + j0;
        float4 b0 = *(const float4*)brow;
        float4 b1 = *(const float4*)(brow + 4);
        e[r][0] = __expf(b0.x - uo - vr[0]);
        e[r][1] = __expf(b0.y - uo - vr[1]);
        e[r][2] = __expf(b0.z - uo - vr[2]);
        e[r][3] = __expf(b0.w - uo - vr[3]);
        e[r][4] = __expf(b1.x - uo - vr[4]);
        e[r][5] = __expf(b1.y - uo - vr[5]);
        e[r][6] = __expf(b1.z - uo - vr[6]);
        e[r][7] = __expf(b1.w - uo - vr[7]);
        #pragma unroll
        for (int q = 0; q < 8; ++q) ls += e[r][q];
      }
      #pragma unroll
      for (int off = 32; off; off >>= 1) ls += __shfl_down(ls, off, 64);
      if (lane == 0) pr[r][wave] = ls;
    }
    __syncthreads();
    if (t < GR) {
      float S = (pr[t][0] + pr[t][1]) + (pr[t][2] + pr[t][3]);
      Sr[t] = S;
      u[s * P + ic * RPC + g * GR + t] += __logf(S);
    }
    __syncthreads();
    if (act) {
      #pragma unroll
      for (int r = 0; r < GR; ++r) {
        float rs = 1.0f / Sr[r];
        #pragma unroll
        for (int q = 0; q < 8; ++q) acc[q] += e[r][q] * rs;
      }
    }
  }
  if (act) {
    float* pp = ps + ((size_t)(s * IC2 + ic)) * 2048 + j0;
    ((float4*)pp)[0] = make_float4(acc[0], acc[1], acc[2], acc[3]);
    ((float4*)pp)[1] = make_float4(acc[4], acc[5], acc[6], acc[7]);
  }
}

// v_new_j = v_old_j + log(sum_c ps[s][c][j]) over IC2=100 chunks (R8 config)
__global__ void k_combine(const float* __restrict__ ps, float* __restrict__ v) {
  int j = blockIdx.x * 256 + threadIdx.x;
  int s = blockIdx.y;
  if (j >= P) return;
  float S = 0.f;
  for (int c = 0; c < IC2; ++c) S += ps[((size_t)(s * IC2 + c)) * 2048 + j];
  v[s * P + j] += __logf(S);
}

// build-combine over ICB=200 chunks (compile-time bound)
__global__ void k_combineB(const float* __restrict__ ps, float* __restrict__ v) {
  int j = blockIdx.x * 256 + threadIdx.x;
  int s = blockIdx.y;
  if (j >= P) return;
  float S = 0.f;
  for (int c = 0; c < ICB; ++c) S += ps[((size_t)(s * ICB + c)) * 2048 + j];
  v[s * P + j] += __logf(S);
}

// theta[s,i,j] = exp(base - u - v) for all 8 samples; fused mean -> thp
// (R8 config: grid 1000 x 256, 250 active threads)
__global__ void __launch_bounds__(256) k_theta_mean(const float* __restrict__ base,
    const float* __restrict__ u, const float* __restrict__ v,
    float* __restrict__ th, float* __restrict__ thp) {
  int i = blockIdx.x, t = threadIdx.x;
  if (t >= 250) return;
  int j0 = t * 4;
  float4 acc = make_float4(0.f, 0.f, 0.f, 0.f);
  #pragma unroll
  for (int s = 0; s < NS; ++s) {
    float ui = u[s * P + i];
    float4 b = *(const float4*)(base + ((size_t)s * P + i) * P + j0);
    float4 vv = *(const float4*)(v + s * P + j0);
    float4 t4;
    t4.x = __expf(b.x - ui - vv.x);
    t4.y = __expf(b.y - ui - vv.y);
    t4.z = __expf(b.z - ui - vv.z);
    t4.w = __expf(b.w - ui - vv.w);
    *(float4*)(th + ((size_t)s * N_NODES + i) * N_NODES + j0) = t4;
    acc.x += t4.x; acc.y += t4.y; acc.z += t4.z; acc.w += t4.w;
  }
  acc.x *= 0.125f; acc.y *= 0.125f; acc.z *= 0.125f; acc.w *= 0.125f;
  *(float4*)(thp + (size_t)i * N_NODES + j0) = acc;
}

// fused reward, XCD-affinity: s = blockIdx.x & 7 so all blocks touching
// theta[s] (4 MB = one XCD L2) land on the same XCD (id%8 round-robin).
__global__ void __launch_bounds__(256) k_reward(const float* __restrict__ th,
    const int* __restrict__ startA, const int* __restrict__ partA,
    const int* __restrict__ epackD, float* __restrict__ matched) {
  __shared__ float yrow[N_NODES];
  __shared__ float xrow[N_NODES];
  int s = blockIdx.x & 7, b = blockIdx.x >> 3;
  int t = threadIdx.x;
  const float* xr = th + ((size_t)s * N_NODES + b) * N_NODES;
  float4 y4 = make_float4(0.f, 0.f, 0.f, 0.f);
  if (t < 250) {
    ((float4*)xrow)[t] = ((const float4*)xr)[t];
    int e0 = startA[b], e1 = startA[b + 1];
    for (int q = e0; q < e1; ++q) {
      float4 vv = ((const float4*)(th + ((size_t)s * N_NODES + partA[q]) * N_NODES))[t];
      y4.x += vv.x; y4.y += vv.y; y4.z += vv.z; y4.w += vv.w;
    }
    ((float4*)yrow)[t] = y4;
  }
  __syncthreads();
  float acc = 0.f;
  for (int m = t; m < N_EDGES; m += 256) {
    int pk = epackD[m];
    acc += yrow[pk >> 10] * xrow[pk & 1023];
  }
  float ssum = blockSum256(acc);
  if (t == 0) atomicAdd(matched + s, ssum);
}

__global__ void k_fin0(const float* __restrict__ matched, float* __restrict__ scal) {
  if (threadIdx.x == 0) {
    float accm = 0.f;
    for (int s = 0; s < NS; ++s) {
      float m = matched[s];
      float rv = m + (-1.0f) * ((16000.0f - m) + (16000.0f - m));
      accm += rv;
    }
    scal[0] = (accm / 8.0f) / 16000.0f;
  }
}

__global__ void k_fin1(const float* __restrict__ matched, float* __restrict__ scal,
                       float* __restrict__ out) {
  if (threadIdx.x == 0) {
    float accm = 0.f;
    for (int s = 0; s < NS; ++s) {
      float m = matched[s];
      float rv = m + (-1.0f) * ((16000.0f - m) + (16000.0f - m));
      accm += rv;
    }
    float r1 = (accm / 8.0f) / 16000.0f;
    float r0 = scal[0];
    int improved = (r1 > r0) ? 1 : 0;
    scal[1] = r1;
    scal[2] = (float)improved;
    float loss = -r0 - (improved ? r1 : 0.f);
    float cnt = improved ? 2.0f : 1.0f;
    out[(size_t)P * P] = loss / cnt;
  }
}

__global__ void k_out_sel(const float* __restrict__ laA, const float* __restrict__ laB,
                          const float* __restrict__ scal, float* __restrict__ out) {
  int q = blockIdx.x * 256 + threadIdx.x;
  if (q >= P * P / 4) return;
  const float* la = (scal[2] != 0.0f) ? laB : laA;
  int row = q / (P / 4);
  int jc = (q % (P / 4)) * 4;
  float4 vv = make_float4(0.f, 0.f, 0.f, 0.f);
  if (row < N_NODES && jc < N_NODES)
    vv = *(const float4*)(la + (size_t)row * N_NODES + jc);
  *(float4*)(out + (size_t)row * P + jc) = vv;
}

// ---------------- launch ----------------
extern "C" void kernel_launch(void* const* d_in, const int* in_sizes, int n_in,
                              void* d_out, int out_size, void* d_ws, size_t ws_size,
                              hipStream_t stream) {
  (void)in_sizes; (void)n_in; (void)out_size; (void)ws_size;
  const float* x_s = (const float*)d_in[0];
  const int*   e_s = (const int*)d_in[1];
  const float* x_t = (const float*)d_in[2];
  const int*   e_t = (const int*)d_in[3];
  const float* W1  = (const float*)d_in[4];
  const float* b1  = (const float*)d_in[5];
  const float* W2  = (const float*)d_in[6];
  const float* b2  = (const float*)d_in[7];
  float* out = (float*)d_out;

  float* ws    = (float*)d_ws;
  float* base  = ws;                       // 32,000,000
  float* theta = base + 32000000;          //  8,000,000
  float* laA   = theta + 8000000;          //  1,000,000
  float* laB   = laA + 1000000;            //  1,000,000
  float* thp   = laB + 1000000;            //  1,000,000
  float* h0    = thp + 1000000;            //    512,000
  float* agg   = h0 + 512000;
  float* h1    = agg + 512000;
  float* h2    = h1 + 512000;
  float* hn    = h2 + 512000;
  float* uarr  = hn + 512000;              //     16,000
  float* varr  = uarr + 16000;             //     16,000
  float* ps    = varr + 16000;             //  3,276,800 (ICB*NS*2048 max)
  float* imp   = ps + 3276800;             //      2,048
  float* matched = imp + 2048;             //         16
  float* scal  = matched + 16;             //         16
  int* ibase  = (int*)(scal + 16);
  int* cnt    = ibase;                     // 1,024
  int* cursor = cnt + 1024;                // 1,024
  int* ids    = cursor + 1024;             // 16,000
  int* startA = ids + 16000;               // 1,008
  int* startB = startA + 1008;             // 1,008
  int* partA  = startB + 1008;             // 16,000
  int* partB  = partA + 16000;             // 16,000
  int* epackD = partB + 16000;             // 16,000

  const int* keys[2]  = { e_s + N_EDGES, e_t + N_EDGES };
  const int* parts[2] = { e_s,           e_t           };
  int* outs_s[2] = { startA, startB };
  int* outs_p[2] = { partA,  partB  };
  for (int r = 0; r < 2; ++r) {
    hipMemsetAsync(cnt, 0, 2048 * sizeof(int), stream);
    k_hist<<<63, 256, 0, stream>>>(keys[r], cnt);
    k_scan<<<1, 1024, 0, stream>>>(cnt, outs_s[r]);
    k_scatter<<<63, 256, 0, stream>>>(keys[r], outs_s[r], cursor, ids);
    k_partfill<<<63, 256, 0, stream>>>(ids, parts[r], outs_p[r]);
  }
  k_packD<<<4, 256, 0, stream>>>(startB, partB, epackD);

  uint32_t k0 = 0u, k1 = 42u;
  uint32_t sub[2][2];
  for (int it = 0; it < 2; ++it) {
    uint32_t nk0, nk1, s0, s1;
    tf2x32(k0, k1, 0u, 0u, &nk0, &nk1);
    tf2x32(k0, k1, 0u, 1u, &s0, &s1);
    sub[it][0] = s0; sub[it][1] = s1;
    k0 = nk0; k1 = nk1;
  }

  for (int it = 0; it < 2; ++it) {
    if (it == 0) {
      k_ones<<<8, 256, 0, stream>>>(imp);
    } else {
      k_rowsum<<<N_NODES, 256, 0, stream>>>(thp, imp);
      hipMemsetAsync(imp + 1024, 0, 1024 * sizeof(float), stream);
      k_colsum<<<dim3(4, 8), 256, 0, stream>>>(thp, imp);
    }
    k_scale_b<<<dim3(N_NODES, 2), 256, 0, stream>>>(x_s, x_t, imp, h0);
    k_agg_b<<<dim3(N_NODES, 2), 256, 0, stream>>>(h0, startA, partA, agg);
    k_lin_b<<<dim3(63, 4, 2), 256, 0, stream>>>(h0, agg, W1, b1, h1, 1);
    k_agg_b<<<dim3(N_NODES, 2), 256, 0, stream>>>(h1, startA, partA, agg);
    k_lin_b<<<dim3(63, 4, 2), 256, 0, stream>>>(h1, agg, W2, b2, h2, 0);
    k_norm_b<<<dim3(N_NODES, 2), 256, 0, stream>>>(h2, hn);
    float* la = it ? laB : laA;
    k_gemm50<<<dim3(16, 16), 256, 0, stream>>>(hn, hn + 256000, la);

    // sinkhorn: build(ICB=200) + 9 fused(IC2=100) passes (R8 config)
    hipMemsetAsync(varr, 0, NS * P * sizeof(float), stream);
    k_build<<<dim3(ICB, NS), 256, 0, stream>>>(la, base, uarr, ps,
                                               sub[it][0], sub[it][1]);
    k_combineB<<<dim3(8, NS), 256, 0, stream>>>(ps, varr);
    for (int k = 0; k < 9; ++k) {
      k_fused<<<dim3(IC2, NS), 256, 0, stream>>>(base, varr, uarr, ps);
      k_combine<<<dim3(8, NS), 256, 0, stream>>>(ps, varr);
    }

    k_theta_mean<<<N_NODES, 256, 0, stream>>>(base, uarr, varr, theta, thp);
    hipMemsetAsync(matched, 0, NS * 4, stream);
    k_reward<<<8000, 256, 0, stream>>>(theta, startA, partA, epackD, matched);
    if (it == 0) k_fin0<<<1, 64, 0, stream>>>(matched, scal);
    else         k_fin1<<<1, 64, 0, stream>>>(matched, scal, out);
  }
  k_out_sel<<<3907, 256, 0, stream>>>(laA, laB, scal, out);
}

// Round 13
// 1285.454 us; speedup vs baseline: 1.4327x; 1.0929x over previous
//
#include <hip/hip_runtime.h>
#include <stdint.h>
#include <math.h>

#define N_NODES 1000
#define DIM 256
#define N_EDGES 16000
#define NS 8            // gumbel samples
#define P 2000          // padded sinkhorn size
#define IC2 100         // row chunks for k_fused (R8 measured config)
#define RPC (P / IC2)   // rows per fused chunk = 20
#define ICB 200         // row chunks for k_build (measured: 160->135us)
#define RPB (P / ICB)   // rows per build chunk = 10
#define GR 5            // rows per register-group in k_fused

// ---------------- bf16 helpers (RNE) ----------------
__device__ inline unsigned short f2bf(float f) {
  uint32_t x = __float_as_uint(f);
  uint32_t r = (x + 0x7FFFu + ((x >> 16) & 1u)) >> 16;
  return (unsigned short)r;
}
__device__ inline float bf2f(unsigned short u) {
  return __uint_as_float(((uint32_t)u) << 16);
}

// ---------------- Threefry-2x32 (exact JAX) ----------------
__host__ __device__ inline void tf2x32(uint32_t k0, uint32_t k1,
                                       uint32_t x0, uint32_t x1,
                                       uint32_t* o0, uint32_t* o1) {
  const uint32_t ks2 = k0 ^ k1 ^ 0x1BD11BDAu;
  uint32_t a = x0 + k0, b = x1 + k1;
#define RL(v, d) (((v) << (d)) | ((v) >> (32 - (d))))
#define RND(r) { a += b; b = RL(b, r); b ^= a; }
  RND(13) RND(15) RND(26) RND(6)
  a += k1;  b += ks2 + 1u;
  RND(17) RND(29) RND(16) RND(24)
  a += ks2; b += k0 + 2u;
  RND(13) RND(15) RND(26) RND(6)
  a += k0;  b += k1 + 3u;
  RND(17) RND(29) RND(16) RND(24)
  a += k1;  b += ks2 + 4u;
  RND(13) RND(15) RND(26) RND(6)
  a += ks2; b += k0 + 5u;
#undef RND
#undef RL
  *o0 = a; *o1 = b;
}

__device__ inline float gumbel_from_idx(uint32_t k0, uint32_t k1, uint32_t idx) {
  uint32_t b0, b1;
  tf2x32(k0, k1, 0u, idx, &b0, &b1);
  uint32_t bits = b0 ^ b1;
  float u = __uint_as_float((bits >> 9) | 0x3f800000u) - 1.0f;
  return -__logf(-__logf(u + 1e-20f) + 1e-20f);
}

// ---------------- block reductions (blockDim==256) ----------------
__device__ inline float blockSum256(float v) {
  __shared__ float sm[4];
  #pragma unroll
  for (int off = 32; off; off >>= 1) v += __shfl_down(v, off, 64);
  if ((threadIdx.x & 63) == 0) sm[threadIdx.x >> 6] = v;
  __syncthreads();
  float r = (sm[0] + sm[1]) + (sm[2] + sm[3]);
  __syncthreads();
  return r;
}
__device__ inline float blockMax256(float v) {
  __shared__ float sm[4];
  #pragma unroll
  for (int off = 32; off; off >>= 1) v = fmaxf(v, __shfl_down(v, off, 64));
  if ((threadIdx.x & 63) == 0) sm[threadIdx.x >> 6] = v;
  __syncthreads();
  float r = fmaxf(fmaxf(sm[0], sm[1]), fmaxf(sm[2], sm[3]));
  __syncthreads();
  return r;
}

// ---------------- CSR build ----------------
__global__ void k_hist(const int* __restrict__ key, int* __restrict__ cnt) {
  int k = blockIdx.x * 256 + threadIdx.x;
  if (k < N_EDGES) atomicAdd(&cnt[key[k]], 1);
}
__global__ void k_scan(const int* __restrict__ cnt, int* __restrict__ start) {
  __shared__ int sm[1024];
  int t = threadIdx.x;
  sm[t] = (t < N_NODES) ? cnt[t] : 0;
  __syncthreads();
  for (int off = 1; off < 1024; off <<= 1) {
    int v = (t >= off) ? sm[t - off] : 0;
    __syncthreads();
    sm[t] += v;
    __syncthreads();
  }
  if (t < N_NODES) start[t + 1] = sm[t];
  if (t == 0) start[0] = 0;
}
__global__ void k_scatter(const int* __restrict__ key, const int* __restrict__ start,
                          int* __restrict__ cursor, int* __restrict__ ids) {
  int k = blockIdx.x * 256 + threadIdx.x;
  if (k < N_EDGES) {
    int c = key[k];
    int slot = start[c] + atomicAdd(&cursor[c], 1);
    ids[slot] = k;
  }
}
__global__ void k_partfill(const int* __restrict__ ids, const int* __restrict__ pv,
                           int* __restrict__ part) {
  int s = blockIdx.x * 256 + threadIdx.x;
  if (s < N_EDGES) part[s] = pv[ids[s]];
}
__global__ void k_packD(const int* __restrict__ startB, const int* __restrict__ partB,
                        int* __restrict__ epackD) {
  int d = blockIdx.x * 256 + threadIdx.x;
  if (d >= N_NODES) return;
  int e0 = startB[d], e1 = startB[d + 1];
  for (int q = e0; q < e1; ++q) epackD[q] = (d << 10) | partB[q];
}

// ---------------- small kernels ----------------
__global__ void k_ones(float* imp) {
  int t = blockIdx.x * 256 + threadIdx.x;
  if (t < 2048) imp[t] = 1.0f;
}

__global__ void k_rowsum(const float* __restrict__ thp, float* __restrict__ imp) {
  int i = blockIdx.x;
  float a = 0.f;
  for (int j = threadIdx.x; j < N_NODES; j += 256) a += thp[(size_t)i * N_NODES + j];
  float s = blockSum256(a);
  if (threadIdx.x == 0) imp[i] = s;
}

__global__ void k_colsum(const float* __restrict__ thp, float* __restrict__ imp) {
  int j = blockIdx.x * 256 + threadIdx.x;
  if (j >= N_NODES) return;
  int r0 = blockIdx.y * 125;
  float a = 0.f;
  for (int i = r0; i < r0 + 125; ++i) a += thp[(size_t)i * N_NODES + j];
  atomicAdd(&imp[1024 + j], a);
}

__global__ void k_scale_b(const float* __restrict__ xs, const float* __restrict__ xt,
                          const float* __restrict__ imp, float* __restrict__ h) {
  int g = blockIdx.y, i = blockIdx.x, d = threadIdx.x;
  const float* x = g ? xt : xs;
  h[(size_t)g * 256000 + i * DIM + d] = x[i * DIM + d] * imp[g * 1024 + i];
}

__global__ void k_agg_b(const float* __restrict__ h, const int* __restrict__ start,
                        const int* __restrict__ part, float* __restrict__ agg) {
  int g = blockIdx.y, i = blockIdx.x, d = threadIdx.x;
  const int* st = start + g * 1008;
  const int* pt = part + g * 16000;
  const float* hh = h + (size_t)g * 256000;
  int e0 = st[i], e1 = st[i + 1];
  float a = 0.f;
  for (int q = e0; q < e1; ++q) a += hh[(size_t)pt[q] * DIM + d];
  agg[(size_t)g * 256000 + i * DIM + d] = a;
}

__global__ void __launch_bounds__(256) k_lin_b(const float* __restrict__ h_,
    const float* __restrict__ agg_, const float* __restrict__ Wm,
    const float* __restrict__ bias, float* __restrict__ out_, int relu) {
  __shared__ float As[16][64];
  __shared__ float Ws[64][64];
  int g = blockIdx.z;
  const float* h   = h_   + (size_t)g * 256000;
  const float* agg = agg_ + (size_t)g * 256000;
  float* out       = out_ + (size_t)g * 256000;
  int tx = threadIdx.x & 63;
  int ty = threadIdx.x >> 6;
  int row0 = blockIdx.x * 16;
  int col0 = blockIdx.y * 64;
  float acc[4] = {0.f, 0.f, 0.f, 0.f};
  for (int kc = 0; kc < DIM; kc += 64) {
    for (int t = threadIdx.x; t < 16 * 64; t += 256) {
      int r = t >> 6, c = t & 63;
      int gr = row0 + r;
      As[r][c] = (gr < N_NODES) ? (h[gr * DIM + kc + c] + agg[gr * DIM + kc + c]) : 0.f;
    }
    for (int t = threadIdx.x; t < 64 * 64; t += 256) {
      int r = t >> 6, c = t & 63;
      Ws[r][c] = Wm[(kc + r) * DIM + col0 + c];
    }
    __syncthreads();
    #pragma unroll 8
    for (int kk = 0; kk < 64; ++kk) {
      float w = Ws[kk][tx];
      acc[0] += As[ty][kk] * w;
      acc[1] += As[ty + 4][kk] * w;
      acc[2] += As[ty + 8][kk] * w;
      acc[3] += As[ty + 12][kk] * w;
    }
    __syncthreads();
  }
  int col = col0 + tx;
  float bv = bias[col];
  #pragma unroll
  for (int r = 0; r < 4; ++r) {
    int gr = row0 + ty + r * 4;
    if (gr < N_NODES) {
      float vv = acc[r] + bv;
      if (relu) vv = fmaxf(vv, 0.f);
      out[gr * DIM + col] = vv;
    }
  }
}

__global__ void k_norm_b(const float* __restrict__ h, float* __restrict__ out) {
  int g = blockIdx.y, i = blockIdx.x;
  float x = h[(size_t)g * 256000 + i * DIM + threadIdx.x];
  float ss = blockSum256(x * x);
  float nrm = sqrtf(ss);
  out[(size_t)g * 256000 + i * DIM + threadIdx.x] = x / nrm;
}

__global__ void __launch_bounds__(256) k_gemm50(const float* __restrict__ A,
    const float* __restrict__ B, float* __restrict__ C) {
  __shared__ float As[64][33];
  __shared__ float Bs[64][33];
  int tr = threadIdx.x >> 4;
  int tc = threadIdx.x & 15;
  int i0 = blockIdx.x * 64, j0 = blockIdx.y * 64;
  float acc[4][4] = {};
  for (int kc = 0; kc < DIM; kc += 32) {
    for (int t = threadIdx.x; t < 64 * 32; t += 256) {
      int r = t >> 5, c = t & 31;
      int gi = i0 + r; As[r][c] = (gi < N_NODES) ? A[gi * DIM + kc + c] : 0.f;
      int gj = j0 + r; Bs[r][c] = (gj < N_NODES) ? B[gj * DIM + kc + c] : 0.f;
    }
    __syncthreads();
    for (int kk = 0; kk < 32; ++kk) {
      float a[4], b[4];
      #pragma unroll
      for (int q = 0; q < 4; ++q) a[q] = As[tr * 4 + q][kk];
      #pragma unroll
      for (int q = 0; q < 4; ++q) b[q] = Bs[tc * 4 + q][kk];
      #pragma unroll
      for (int r = 0; r < 4; ++r)
        #pragma unroll
        for (int c = 0; c < 4; ++c) acc[r][c] += a[r] * b[c];
    }
    __syncthreads();
  }
  for (int r = 0; r < 4; ++r) {
    int gi = i0 + tr * 4 + r;
    if (gi >= N_NODES) continue;
    for (int c = 0; c < 4; ++c) {
      int gj = j0 + tc * 4 + c;
      if (gj < N_NODES) C[(size_t)gi * N_NODES + gj] = 50.0f * acc[r][c];
    }
  }
}

// build: Q = exp(b - u1) stored bf16 (row-normalized residual, in [0,1]);
// v1 col-partials from unrounded values. du starts at 0 (memset by host).
__global__ void __launch_bounds__(256) k_build(const float* __restrict__ la,
    unsigned short* __restrict__ Q, float* __restrict__ ps,
    uint32_t k0, uint32_t k1) {
  int ic = blockIdx.x, s = blockIdx.y;
  int t = threadIdx.x;
  int j0 = t * 8;
  bool act = (j0 < P);
  float acc[8] = {0.f,0.f,0.f,0.f,0.f,0.f,0.f,0.f};
  for (int r = 0; r < RPB; ++r) {
    int i = ic * RPB + r;
    float bv[8];
    float lmax = -INFINITY;
    if (act) {
      uint32_t idxbase = (uint32_t)((s * P + i) * P + j0);
      #pragma unroll
      for (int q = 0; q < 8; ++q) {
        int j = j0 + q;
        float g = gumbel_from_idx(k0, k1, idxbase + (uint32_t)q);
        float lav = (i < N_NODES && j < N_NODES) ? la[(size_t)i * N_NODES + j] : 0.0f;
        bv[q] = (lav + g) * 10.0f;
        lmax = fmaxf(lmax, bv[q]);
      }
    }
    float M = blockMax256(lmax);
    float e[8];
    float ls = 0.f;
    if (act) {
      #pragma unroll
      for (int q = 0; q < 8; ++q) { e[q] = __expf(bv[q] - M); ls += e[q]; }
    }
    float S = blockSum256(ls);
    if (act) {
      float rs = 1.0f / S;
      unsigned short q8[8];
      #pragma unroll
      for (int q = 0; q < 8; ++q) {
        float val = e[q] * rs;
        acc[q] += val;
        q8[q] = f2bf(val);
      }
      ushort4* qp = (ushort4*)(Q + ((size_t)s * P + i) * P + j0);
      qp[0] = make_ushort4(q8[0], q8[1], q8[2], q8[3]);
      qp[1] = make_ushort4(q8[4], q8[5], q8[6], q8[7]);
    }
  }
  if (act) {
    float* pp = ps + ((size_t)(s * ICB + ic)) * 2048 + j0;
    ((float4*)pp)[0] = make_float4(acc[0], acc[1], acc[2], acc[3]);
    ((float4*)pp)[1] = make_float4(acc[4], acc[5], acc[6], acc[7]);
  }
}

// fused sinkhorn pass on bf16 Q: e = Q*exp(-du_i)*exp(-dv_j).
// col-factors ev[8] precomputed once; 1 exp per row (edu). HBM-bound.
__global__ void __launch_bounds__(256) k_fused(const unsigned short* __restrict__ Q,
    const float* __restrict__ dv, float* __restrict__ du, float* __restrict__ ps) {
  int ic = blockIdx.x, s = blockIdx.y;
  int t = threadIdx.x;
  int lane = t & 63, wave = t >> 6;
  int j0 = t * 8;
  bool act = (j0 < P);
  __shared__ float pr[GR][4];
  __shared__ float Sr[GR];
  float ev[8];
  if (act) {
    float4 v0 = *(const float4*)(dv + s * P + j0);
    float4 v1 = *(const float4*)(dv + s * P + j0 + 4);
    ev[0] = __expf(-v0.x); ev[1] = __expf(-v0.y);
    ev[2] = __expf(-v0.z); ev[3] = __expf(-v0.w);
    ev[4] = __expf(-v1.x); ev[5] = __expf(-v1.y);
    ev[6] = __expf(-v1.z); ev[7] = __expf(-v1.w);
  }
  float acc[8] = {0.f,0.f,0.f,0.f,0.f,0.f,0.f,0.f};
  for (int g = 0; g < RPC / GR; ++g) {
    float e[GR][8];
    #pragma unroll
    for (int r = 0; r < GR; ++r) {
      int i = ic * RPC + g * GR + r;
      float edu = __expf(-du[s * P + i]);
      float ls = 0.f;
      if (act) {
        const unsigned short* qrow = Q + ((size_t)s * P + i) * P + j0;
        ushort4 a = *(const ushort4*)qrow;
        ushort4 b = *(const ushort4*)(qrow + 4);
        e[r][0] = bf2f(a.x) * edu * ev[0];
        e[r][1] = bf2f(a.y) * edu * ev[1];
        e[r][2] = bf2f(a.z) * edu * ev[2];
        e[r][3] = bf2f(a.w) * edu * ev[3];
        e[r][4] = bf2f(b.x) * edu * ev[4];
        e[r][5] = bf2f(b.y) * edu * ev[5];
        e[r][6] = bf2f(b.z) * edu * ev[6];
        e[r][7] = bf2f(b.w) * edu * ev[7];
        #pragma unroll
        for (int q = 0; q < 8; ++q) ls += e[r][q];
      }
      #pragma unroll
      for (int off = 32; off; off >>= 1) ls += __shfl_down(ls, off, 64);
      if (lane == 0) pr[r][wave] = ls;
    }
    __syncthreads();
    if (t < GR) {
      float S = (pr[t][0] + pr[t][1]) + (pr[t][2] + pr[t][3]);
      Sr[t] = S;
      du[s * P + ic * RPC + g * GR + t] += __logf(S);
    }
    __syncthreads();
    if (act) {
      #pragma unroll
      for (int r = 0; r < GR; ++r) {
        float rs = 1.0f / Sr[r];
        #pragma unroll
        for (int q = 0; q < 8; ++q) acc[q] += e[r][q] * rs;
      }
    }
  }
  if (act) {
    float* pp = ps + ((size_t)(s * IC2 + ic)) * 2048 + j0;
    ((float4*)pp)[0] = make_float4(acc[0], acc[1], acc[2], acc[3]);
    ((float4*)pp)[1] = make_float4(acc[4], acc[5], acc[6], acc[7]);
  }
}

// dv_new_j = dv_old_j + log(sum_c ps[s][c][j]) over IC2=100 chunks
__global__ void k_combine(const float* __restrict__ ps, float* __restrict__ v) {
  int j = blockIdx.x * 256 + threadIdx.x;
  int s = blockIdx.y;
  if (j >= P) return;
  float S = 0.f;
  for (int c = 0; c < IC2; ++c) S += ps[((size_t)(s * IC2 + c)) * 2048 + j];
  v[s * P + j] += __logf(S);
}

// build-combine over ICB=200 chunks
__global__ void k_combineB(const float* __restrict__ ps, float* __restrict__ v) {
  int j = blockIdx.x * 256 + threadIdx.x;
  int s = blockIdx.y;
  if (j >= P) return;
  float S = 0.f;
  for (int c = 0; c < ICB; ++c) S += ps[((size_t)(s * ICB + c)) * 2048 + j];
  v[s * P + j] += __logf(S);
}

// theta[s,i,j] = Q*exp(-du-dv) -> bf16; fused fp32 mean -> thp
__global__ void __launch_bounds__(256) k_theta_mean(const unsigned short* __restrict__ Q,
    const float* __restrict__ du, const float* __restrict__ dv,
    unsigned short* __restrict__ th, float* __restrict__ thp) {
  int i = blockIdx.x, t = threadIdx.x;
  if (t >= 250) return;
  int j0 = t * 4;
  float4 acc = make_float4(0.f, 0.f, 0.f, 0.f);
  #pragma unroll
  for (int s = 0; s < NS; ++s) {
    float duo = du[s * P + i];
    ushort4 q4 = *(const ushort4*)(Q + ((size_t)s * P + i) * P + j0);
    float4 vv = *(const float4*)(dv + s * P + j0);
    float t0 = bf2f(q4.x) * __expf(-duo - vv.x);
    float t1 = bf2f(q4.y) * __expf(-duo - vv.y);
    float t2 = bf2f(q4.z) * __expf(-duo - vv.z);
    float t3 = bf2f(q4.w) * __expf(-duo - vv.w);
    *(ushort4*)(th + ((size_t)s * N_NODES + i) * N_NODES + j0) =
        make_ushort4(f2bf(t0), f2bf(t1), f2bf(t2), f2bf(t3));
    acc.x += t0; acc.y += t1; acc.z += t2; acc.w += t3;
  }
  acc.x *= 0.125f; acc.y *= 0.125f; acc.z *= 0.125f; acc.w *= 0.125f;
  *(float4*)(thp + (size_t)i * N_NODES + j0) = acc;
}

// fused reward on bf16 theta, XCD-affinity (s = blockIdx.x & 7)
__global__ void __launch_bounds__(256) k_reward(const unsigned short* __restrict__ th,
    const int* __restrict__ startA, const int* __restrict__ partA,
    const int* __restrict__ epackD, float* __restrict__ matched) {
  __shared__ float yrow[N_NODES];
  __shared__ float xrow[N_NODES];
  int s = blockIdx.x & 7, b = blockIdx.x >> 3;
  int t = threadIdx.x;
  const unsigned short* xr = th + ((size_t)s * N_NODES + b) * N_NODES;
  float4 y4 = make_float4(0.f, 0.f, 0.f, 0.f);
  if (t < 250) {
    ushort4 x4 = ((const ushort4*)xr)[t];
    ((float4*)xrow)[t] = make_float4(bf2f(x4.x), bf2f(x4.y), bf2f(x4.z), bf2f(x4.w));
    int e0 = startA[b], e1 = startA[b + 1];
    for (int q = e0; q < e1; ++q) {
      ushort4 v4 = ((const ushort4*)(th + ((size_t)s * N_NODES + partA[q]) * N_NODES))[t];
      y4.x += bf2f(v4.x); y4.y += bf2f(v4.y); y4.z += bf2f(v4.z); y4.w += bf2f(v4.w);
    }
    ((float4*)yrow)[t] = y4;
  }
  __syncthreads();
  float acc = 0.f;
  for (int m = t; m < N_EDGES; m += 256) {
    int pk = epackD[m];
    acc += yrow[pk >> 10] * xrow[pk & 1023];
  }
  float ssum = blockSum256(acc);
  if (t == 0) atomicAdd(matched + s, ssum);
}

__global__ void k_fin0(const float* __restrict__ matched, float* __restrict__ scal) {
  if (threadIdx.x == 0) {
    float accm = 0.f;
    for (int s = 0; s < NS; ++s) {
      float m = matched[s];
      float rv = m + (-1.0f) * ((16000.0f - m) + (16000.0f - m));
      accm += rv;
    }
    scal[0] = (accm / 8.0f) / 16000.0f;
  }
}

__global__ void k_fin1(const float* __restrict__ matched, float* __restrict__ scal,
                       float* __restrict__ out) {
  if (threadIdx.x == 0) {
    float accm = 0.f;
    for (int s = 0; s < NS; ++s) {
      float m = matched[s];
      float rv = m + (-1.0f) * ((16000.0f - m) + (16000.0f - m));
      accm += rv;
    }
    float r1 = (accm / 8.0f) / 16000.0f;
    float r0 = scal[0];
    int improved = (r1 > r0) ? 1 : 0;
    scal[1] = r1;
    scal[2] = (float)improved;
    float loss = -r0 - (improved ? r1 : 0.f);
    float cnt = improved ? 2.0f : 1.0f;
    out[(size_t)P * P] = loss / cnt;
  }
}

__global__ void k_out_sel(const float* __restrict__ laA, const float* __restrict__ laB,
                          const float* __restrict__ scal, float* __restrict__ out) {
  int q = blockIdx.x * 256 + threadIdx.x;
  if (q >= P * P / 4) return;
  const float* la = (scal[2] != 0.0f) ? laB : laA;
  int row = q / (P / 4);
  int jc = (q % (P / 4)) * 4;
  float4 vv = make_float4(0.f, 0.f, 0.f, 0.f);
  if (row < N_NODES && jc < N_NODES)
    vv = *(const float4*)(la + (size_t)row * N_NODES + jc);
  *(float4*)(out + (size_t)row * P + jc) = vv;
}

// ---------------- launch ----------------
extern "C" void kernel_launch(void* const* d_in, const int* in_sizes, int n_in,
                              void* d_out, int out_size, void* d_ws, size_t ws_size,
                              hipStream_t stream) {
  (void)in_sizes; (void)n_in; (void)out_size; (void)ws_size;
  const float* x_s = (const float*)d_in[0];
  const int*   e_s = (const int*)d_in[1];
  const float* x_t = (const float*)d_in[2];
  const int*   e_t = (const int*)d_in[3];
  const float* W1  = (const float*)d_in[4];
  const float* b1  = (const float*)d_in[5];
  const float* W2  = (const float*)d_in[6];
  const float* b2  = (const float*)d_in[7];
  float* out = (float*)d_out;

  // workspace layout
  unsigned short* Qbuf  = (unsigned short*)d_ws;   // 32,000,000 bf16 (64 MB)
  unsigned short* theta = Qbuf + 32000000;         //  8,000,000 bf16 (16 MB)
  float* laA   = (float*)(theta + 8000000);        //  1,000,000 f32
  float* laB   = laA + 1000000;
  float* thp   = laB + 1000000;
  float* h0    = thp + 1000000;                    //    512,000 (2 graphs)
  float* agg   = h0 + 512000;
  float* h1    = agg + 512000;
  float* h2    = h1 + 512000;
  float* hn    = h2 + 512000;
  float* uarr  = hn + 512000;                      //     16,000 (du)
  float* varr  = uarr + 16000;                     //     16,000 (dv)
  float* ps    = varr + 16000;                     //  3,276,800 (ICB*NS*2048)
  float* imp   = ps + 3276800;                     //      2,048
  float* matched = imp + 2048;
  float* scal  = matched + 16;
  int* cnt    = (int*)(scal + 16);                 // 1,024
  int* cursor = cnt + 1024;                        // 1,024
  int* ids    = cursor + 1024;                     // 16,000
  int* startA = ids + 16000;                       // 1,008
  int* startB = startA + 1008;                     // 1,008
  int* partA  = startB + 1008;                     // 16,000
  int* partB  = partA + 16000;                     // 16,000
  int* epackD = partB + 16000;                     // 16,000

  const int* keys[2]  = { e_s + N_EDGES, e_t + N_EDGES };
  const int* parts[2] = { e_s,           e_t           };
  int* outs_s[2] = { startA, startB };
  int* outs_p[2] = { partA,  partB  };
  for (int r = 0; r < 2; ++r) {
    hipMemsetAsync(cnt, 0, 2048 * sizeof(int), stream);
    k_hist<<<63, 256, 0, stream>>>(keys[r], cnt);
    k_scan<<<1, 1024, 0, stream>>>(cnt, outs_s[r]);
    k_scatter<<<63, 256, 0, stream>>>(keys[r], outs_s[r], cursor, ids);
    k_partfill<<<63, 256, 0, stream>>>(ids, parts[r], outs_p[r]);
  }
  k_packD<<<4, 256, 0, stream>>>(startB, partB, epackD);

  uint32_t k0 = 0u, k1 = 42u;
  uint32_t sub[2][2];
  for (int it = 0; it < 2; ++it) {
    uint32_t nk0, nk1, s0, s1;
    tf2x32(k0, k1, 0u, 0u, &nk0, &nk1);
    tf2x32(k0, k1, 0u, 1u, &s0, &s1);
    sub[it][0] = s0; sub[it][1] = s1;
    k0 = nk0; k1 = nk1;
  }

  for (int it = 0; it < 2; ++it) {
    if (it == 0) {
      k_ones<<<8, 256, 0, stream>>>(imp);
    } else {
      k_rowsum<<<N_NODES, 256, 0, stream>>>(thp, imp);
      hipMemsetAsync(imp + 1024, 0, 1024 * sizeof(float), stream);
      k_colsum<<<dim3(4, 8), 256, 0, stream>>>(thp, imp);
    }
    k_scale_b<<<dim3(N_NODES, 2), 256, 0, stream>>>(x_s, x_t, imp, h0);
    k_agg_b<<<dim3(N_NODES, 2), 256, 0, stream>>>(h0, startA, partA, agg);
    k_lin_b<<<dim3(63, 4, 2), 256, 0, stream>>>(h0, agg, W1, b1, h1, 1);
    k_agg_b<<<dim3(N_NODES, 2), 256, 0, stream>>>(h1, startA, partA, agg);
    k_lin_b<<<dim3(63, 4, 2), 256, 0, stream>>>(h1, agg, W2, b2, h2, 0);
    k_norm_b<<<dim3(N_NODES, 2), 256, 0, stream>>>(h2, hn);
    float* la = it ? laB : laA;
    k_gemm50<<<dim3(16, 16), 256, 0, stream>>>(hn, hn + 256000, la);

    // sinkhorn on bf16 Q: du/dv potentials start at 0
    hipMemsetAsync(uarr, 0, 2 * NS * P * sizeof(float), stream);  // du + dv
    k_build<<<dim3(ICB, NS), 256, 0, stream>>>(la, Qbuf, ps,
                                               sub[it][0], sub[it][1]);
    k_combineB<<<dim3(8, NS), 256, 0, stream>>>(ps, varr);
    for (int k = 0; k < 9; ++k) {
      k_fused<<<dim3(IC2, NS), 256, 0, stream>>>(Qbuf, varr, uarr, ps);
      k_combine<<<dim3(8, NS), 256, 0, stream>>>(ps, varr);
    }

    k_theta_mean<<<N_NODES, 256, 0, stream>>>(Qbuf, uarr, varr, theta, thp);
    hipMemsetAsync(matched, 0, NS * 4, stream);
    k_reward<<<8000, 256, 0, stream>>>(theta, startA, partA, epackD, matched);
    if (it == 0) k_fin0<<<1, 64, 0, stream>>>(matched, scal);
    else         k_fin1<<<1, 64, 0, stream>>>(matched, scal, out);
  }
  k_out_sel<<<3907, 256, 0, stream>>>(laA, laB, scal, out);
}

// Round 14
// 1179.327 us; speedup vs baseline: 1.5616x; 1.0900x over previous
//
#include <hip/hip_runtime.h>
#include <stdint.h>
#include <math.h>

#define N_NODES 1000
#define DIM 256
#define N_EDGES 16000
#define NS 8            // gumbel samples
#define P 2000          // padded sinkhorn size
#define IC2 100         // row chunks for k_fused (R8 measured config)
#define RPC (P / IC2)   // rows per fused chunk = 20
#define ICB 200         // row chunks for k_build (measured: 160->135us)
#define RPB (P / ICB)   // rows per build chunk = 10
#define GR 5            // rows per register-group in k_fused
#define NB 4            // b-rows per reward block (edge-loop amortization)

// ---------------- bf16 helpers (RNE) ----------------
__device__ inline unsigned short f2bf(float f) {
  uint32_t x = __float_as_uint(f);
  uint32_t r = (x + 0x7FFFu + ((x >> 16) & 1u)) >> 16;
  return (unsigned short)r;
}
__device__ inline float bf2f(unsigned short u) {
  return __uint_as_float(((uint32_t)u) << 16);
}

// ---------------- Threefry-2x32 (exact JAX) ----------------
__host__ __device__ inline void tf2x32(uint32_t k0, uint32_t k1,
                                       uint32_t x0, uint32_t x1,
                                       uint32_t* o0, uint32_t* o1) {
  const uint32_t ks2 = k0 ^ k1 ^ 0x1BD11BDAu;
  uint32_t a = x0 + k0, b = x1 + k1;
#define RL(v, d) (((v) << (d)) | ((v) >> (32 - (d))))
#define RND(r) { a += b; b = RL(b, r); b ^= a; }
  RND(13) RND(15) RND(26) RND(6)
  a += k1;  b += ks2 + 1u;
  RND(17) RND(29) RND(16) RND(24)
  a += ks2; b += k0 + 2u;
  RND(13) RND(15) RND(26) RND(6)
  a += k0;  b += k1 + 3u;
  RND(17) RND(29) RND(16) RND(24)
  a += k1;  b += ks2 + 4u;
  RND(13) RND(15) RND(26) RND(6)
  a += ks2; b += k0 + 5u;
#undef RND
#undef RL
  *o0 = a; *o1 = b;
}

__device__ inline float gumbel_from_idx(uint32_t k0, uint32_t k1, uint32_t idx) {
  uint32_t b0, b1;
  tf2x32(k0, k1, 0u, idx, &b0, &b1);
  uint32_t bits = b0 ^ b1;
  float u = __uint_as_float((bits >> 9) | 0x3f800000u) - 1.0f;
  return -__logf(-__logf(u + 1e-20f) + 1e-20f);
}

// ---------------- block reductions (blockDim==256) ----------------
__device__ inline float blockSum256(float v) {
  __shared__ float sm[4];
  #pragma unroll
  for (int off = 32; off; off >>= 1) v += __shfl_down(v, off, 64);
  if ((threadIdx.x & 63) == 0) sm[threadIdx.x >> 6] = v;
  __syncthreads();
  float r = (sm[0] + sm[1]) + (sm[2] + sm[3]);
  __syncthreads();
  return r;
}
__device__ inline float blockMax256(float v) {
  __shared__ float sm[4];
  #pragma unroll
  for (int off = 32; off; off >>= 1) v = fmaxf(v, __shfl_down(v, off, 64));
  if ((threadIdx.x & 63) == 0) sm[threadIdx.x >> 6] = v;
  __syncthreads();
  float r = fmaxf(fmaxf(sm[0], sm[1]), fmaxf(sm[2], sm[3]));
  __syncthreads();
  return r;
}

// ---------------- CSR build ----------------
__global__ void k_hist(const int* __restrict__ key, int* __restrict__ cnt) {
  int k = blockIdx.x * 256 + threadIdx.x;
  if (k < N_EDGES) atomicAdd(&cnt[key[k]], 1);
}
__global__ void k_scan(const int* __restrict__ cnt, int* __restrict__ start) {
  __shared__ int sm[1024];
  int t = threadIdx.x;
  sm[t] = (t < N_NODES) ? cnt[t] : 0;
  __syncthreads();
  for (int off = 1; off < 1024; off <<= 1) {
    int v = (t >= off) ? sm[t - off] : 0;
    __syncthreads();
    sm[t] += v;
    __syncthreads();
  }
  if (t < N_NODES) start[t + 1] = sm[t];
  if (t == 0) start[0] = 0;
}
__global__ void k_scatter(const int* __restrict__ key, const int* __restrict__ start,
                          int* __restrict__ cursor, int* __restrict__ ids) {
  int k = blockIdx.x * 256 + threadIdx.x;
  if (k < N_EDGES) {
    int c = key[k];
    int slot = start[c] + atomicAdd(&cursor[c], 1);
    ids[slot] = k;
  }
}
__global__ void k_partfill(const int* __restrict__ ids, const int* __restrict__ pv,
                           int* __restrict__ part) {
  int s = blockIdx.x * 256 + threadIdx.x;
  if (s < N_EDGES) part[s] = pv[ids[s]];
}
__global__ void k_packD(const int* __restrict__ startB, const int* __restrict__ partB,
                        int* __restrict__ epackD) {
  int d = blockIdx.x * 256 + threadIdx.x;
  if (d >= N_NODES) return;
  int e0 = startB[d], e1 = startB[d + 1];
  for (int q = e0; q < e1; ++q) epackD[q] = (d << 10) | partB[q];
}

// ---------------- small kernels ----------------
__global__ void k_ones(float* imp) {
  int t = blockIdx.x * 256 + threadIdx.x;
  if (t < 2048) imp[t] = 1.0f;
}

__global__ void k_rowsum(const float* __restrict__ thp, float* __restrict__ imp) {
  int i = blockIdx.x;
  float a = 0.f;
  for (int j = threadIdx.x; j < N_NODES; j += 256) a += thp[(size_t)i * N_NODES + j];
  float s = blockSum256(a);
  if (threadIdx.x == 0) imp[i] = s;
}

__global__ void k_colsum(const float* __restrict__ thp, float* __restrict__ imp) {
  int j = blockIdx.x * 256 + threadIdx.x;
  if (j >= N_NODES) return;
  int r0 = blockIdx.y * 125;
  float a = 0.f;
  for (int i = r0; i < r0 + 125; ++i) a += thp[(size_t)i * N_NODES + j];
  atomicAdd(&imp[1024 + j], a);
}

__global__ void k_scale_b(const float* __restrict__ xs, const float* __restrict__ xt,
                          const float* __restrict__ imp, float* __restrict__ h) {
  int g = blockIdx.y, i = blockIdx.x, d = threadIdx.x;
  const float* x = g ? xt : xs;
  h[(size_t)g * 256000 + i * DIM + d] = x[i * DIM + d] * imp[g * 1024 + i];
}

__global__ void k_agg_b(const float* __restrict__ h, const int* __restrict__ start,
                        const int* __restrict__ part, float* __restrict__ agg) {
  int g = blockIdx.y, i = blockIdx.x, d = threadIdx.x;
  const int* st = start + g * 1008;
  const int* pt = part + g * 16000;
  const float* hh = h + (size_t)g * 256000;
  int e0 = st[i], e1 = st[i + 1];
  float a = 0.f;
  for (int q = e0; q < e1; ++q) a += hh[(size_t)pt[q] * DIM + d];
  agg[(size_t)g * 256000 + i * DIM + d] = a;
}

__global__ void __launch_bounds__(256) k_lin_b(const float* __restrict__ h_,
    const float* __restrict__ agg_, const float* __restrict__ Wm,
    const float* __restrict__ bias, float* __restrict__ out_, int relu) {
  __shared__ float As[16][64];
  __shared__ float Ws[64][64];
  int g = blockIdx.z;
  const float* h   = h_   + (size_t)g * 256000;
  const float* agg = agg_ + (size_t)g * 256000;
  float* out       = out_ + (size_t)g * 256000;
  int tx = threadIdx.x & 63;
  int ty = threadIdx.x >> 6;
  int row0 = blockIdx.x * 16;
  int col0 = blockIdx.y * 64;
  float acc[4] = {0.f, 0.f, 0.f, 0.f};
  for (int kc = 0; kc < DIM; kc += 64) {
    for (int t = threadIdx.x; t < 16 * 64; t += 256) {
      int r = t >> 6, c = t & 63;
      int gr = row0 + r;
      As[r][c] = (gr < N_NODES) ? (h[gr * DIM + kc + c] + agg[gr * DIM + kc + c]) : 0.f;
    }
    for (int t = threadIdx.x; t < 64 * 64; t += 256) {
      int r = t >> 6, c = t & 63;
      Ws[r][c] = Wm[(kc + r) * DIM + col0 + c];
    }
    __syncthreads();
    #pragma unroll 8
    for (int kk = 0; kk < 64; ++kk) {
      float w = Ws[kk][tx];
      acc[0] += As[ty][kk] * w;
      acc[1] += As[ty + 4][kk] * w;
      acc[2] += As[ty + 8][kk] * w;
      acc[3] += As[ty + 12][kk] * w;
    }
    __syncthreads();
  }
  int col = col0 + tx;
  float bv = bias[col];
  #pragma unroll
  for (int r = 0; r < 4; ++r) {
    int gr = row0 + ty + r * 4;
    if (gr < N_NODES) {
      float vv = acc[r] + bv;
      if (relu) vv = fmaxf(vv, 0.f);
      out[gr * DIM + col] = vv;
    }
  }
}

__global__ void k_norm_b(const float* __restrict__ h, float* __restrict__ out) {
  int g = blockIdx.y, i = blockIdx.x;
  float x = h[(size_t)g * 256000 + i * DIM + threadIdx.x];
  float ss = blockSum256(x * x);
  float nrm = sqrtf(ss);
  out[(size_t)g * 256000 + i * DIM + threadIdx.x] = x / nrm;
}

__global__ void __launch_bounds__(256) k_gemm50(const float* __restrict__ A,
    const float* __restrict__ B, float* __restrict__ C) {
  __shared__ float As[64][33];
  __shared__ float Bs[64][33];
  int tr = threadIdx.x >> 4;
  int tc = threadIdx.x & 15;
  int i0 = blockIdx.x * 64, j0 = blockIdx.y * 64;
  float acc[4][4] = {};
  for (int kc = 0; kc < DIM; kc += 32) {
    for (int t = threadIdx.x; t < 64 * 32; t += 256) {
      int r = t >> 5, c = t & 31;
      int gi = i0 + r; As[r][c] = (gi < N_NODES) ? A[gi * DIM + kc + c] : 0.f;
      int gj = j0 + r; Bs[r][c] = (gj < N_NODES) ? B[gj * DIM + kc + c] : 0.f;
    }
    __syncthreads();
    for (int kk = 0; kk < 32; ++kk) {
      float a[4], b[4];
      #pragma unroll
      for (int q = 0; q < 4; ++q) a[q] = As[tr * 4 + q][kk];
      #pragma unroll
      for (int q = 0; q < 4; ++q) b[q] = Bs[tc * 4 + q][kk];
      #pragma unroll
      for (int r = 0; r < 4; ++r)
        #pragma unroll
        for (int c = 0; c < 4; ++c) acc[r][c] += a[r] * b[c];
    }
    __syncthreads();
  }
  for (int r = 0; r < 4; ++r) {
    int gi = i0 + tr * 4 + r;
    if (gi >= N_NODES) continue;
    for (int c = 0; c < 4; ++c) {
      int gj = j0 + tc * 4 + c;
      if (gj < N_NODES) C[(size_t)gi * N_NODES + gj] = 50.0f * acc[r][c];
    }
  }
}

// build: Q = exp(b - u1) stored bf16 (row-normalized residual, in [0,1]);
// v1 col-partials from unrounded values. du starts at 0 (memset by host).
__global__ void __launch_bounds__(256) k_build(const float* __restrict__ la,
    unsigned short* __restrict__ Q, float* __restrict__ ps,
    uint32_t k0, uint32_t k1) {
  int ic = blockIdx.x, s = blockIdx.y;
  int t = threadIdx.x;
  int j0 = t * 8;
  bool act = (j0 < P);
  float acc[8] = {0.f,0.f,0.f,0.f,0.f,0.f,0.f,0.f};
  for (int r = 0; r < RPB; ++r) {
    int i = ic * RPB + r;
    float bv[8];
    float lmax = -INFINITY;
    if (act) {
      uint32_t idxbase = (uint32_t)((s * P + i) * P + j0);
      #pragma unroll
      for (int q = 0; q < 8; ++q) {
        int j = j0 + q;
        float g = gumbel_from_idx(k0, k1, idxbase + (uint32_t)q);
        float lav = (i < N_NODES && j < N_NODES) ? la[(size_t)i * N_NODES + j] : 0.0f;
        bv[q] = (lav + g) * 10.0f;
        lmax = fmaxf(lmax, bv[q]);
      }
    }
    float M = blockMax256(lmax);
    float e[8];
    float ls = 0.f;
    if (act) {
      #pragma unroll
      for (int q = 0; q < 8; ++q) { e[q] = __expf(bv[q] - M); ls += e[q]; }
    }
    float S = blockSum256(ls);
    if (act) {
      float rs = 1.0f / S;
      unsigned short q8[8];
      #pragma unroll
      for (int q = 0; q < 8; ++q) {
        float val = e[q] * rs;
        acc[q] += val;
        q8[q] = f2bf(val);
      }
      ushort4* qp = (ushort4*)(Q + ((size_t)s * P + i) * P + j0);
      qp[0] = make_ushort4(q8[0], q8[1], q8[2], q8[3]);
      qp[1] = make_ushort4(q8[4], q8[5], q8[6], q8[7]);
    }
  }
  if (act) {
    float* pp = ps + ((size_t)(s * ICB + ic)) * 2048 + j0;
    ((float4*)pp)[0] = make_float4(acc[0], acc[1], acc[2], acc[3]);
    ((float4*)pp)[1] = make_float4(acc[4], acc[5], acc[6], acc[7]);
  }
}

// fused sinkhorn pass on bf16 Q: e = Q*exp(-du_i)*exp(-dv_j).
__global__ void __launch_bounds__(256) k_fused(const unsigned short* __restrict__ Q,
    const float* __restrict__ dv, float* __restrict__ du, float* __restrict__ ps) {
  int ic = blockIdx.x, s = blockIdx.y;
  int t = threadIdx.x;
  int lane = t & 63, wave = t >> 6;
  int j0 = t * 8;
  bool act = (j0 < P);
  __shared__ float pr[GR][4];
  __shared__ float Sr[GR];
  float ev[8];
  if (act) {
    float4 v0 = *(const float4*)(dv + s * P + j0);
    float4 v1 = *(const float4*)(dv + s * P + j0 + 4);
    ev[0] = __expf(-v0.x); ev[1] = __expf(-v0.y);
    ev[2] = __expf(-v0.z); ev[3] = __expf(-v0.w);
    ev[4] = __expf(-v1.x); ev[5] = __expf(-v1.y);
    ev[6] = __expf(-v1.z); ev[7] = __expf(-v1.w);
  }
  float acc[8] = {0.f,0.f,0.f,0.f,0.f,0.f,0.f,0.f};
  for (int g = 0; g < RPC / GR; ++g) {
    float e[GR][8];
    #pragma unroll
    for (int r = 0; r < GR; ++r) {
      int i = ic * RPC + g * GR + r;
      float edu = __expf(-du[s * P + i]);
      float ls = 0.f;
      if (act) {
        const unsigned short* qrow = Q + ((size_t)s * P + i) * P + j0;
        ushort4 a = *(const ushort4*)qrow;
        ushort4 b = *(const ushort4*)(qrow + 4);
        e[r][0] = bf2f(a.x) * edu * ev[0];
        e[r][1] = bf2f(a.y) * edu * ev[1];
        e[r][2] = bf2f(a.z) * edu * ev[2];
        e[r][3] = bf2f(a.w) * edu * ev[3];
        e[r][4] = bf2f(b.x) * edu * ev[4];
        e[r][5] = bf2f(b.y) * edu * ev[5];
        e[r][6] = bf2f(b.z) * edu * ev[6];
        e[r][7] = bf2f(b.w) * edu * ev[7];
        #pragma unroll
        for (int q = 0; q < 8; ++q) ls += e[r][q];
      }
      #pragma unroll
      for (int off = 32; off; off >>= 1) ls += __shfl_down(ls, off, 64);
      if (lane == 0) pr[r][wave] = ls;
    }
    __syncthreads();
    if (t < GR) {
      float S = (pr[t][0] + pr[t][1]) + (pr[t][2] + pr[t][3]);
      Sr[t] = S;
      du[s * P + ic * RPC + g * GR + t] += __logf(S);
    }
    __syncthreads();
    if (act) {
      #pragma unroll
      for (int r = 0; r < GR; ++r) {
        float rs = 1.0f / Sr[r];
        #pragma unroll
        for (int q = 0; q < 8; ++q) acc[q] += e[r][q] * rs;
      }
    }
  }
  if (act) {
    float* pp = ps + ((size_t)(s * IC2 + ic)) * 2048 + j0;
    ((float4*)pp)[0] = make_float4(acc[0], acc[1], acc[2], acc[3]);
    ((float4*)pp)[1] = make_float4(acc[4], acc[5], acc[6], acc[7]);
  }
}

// dv_new_j = dv_old_j + log(sum_c ps[s][c][j]) over IC2=100 chunks
__global__ void k_combine(const float* __restrict__ ps, float* __restrict__ v) {
  int j = blockIdx.x * 256 + threadIdx.x;
  int s = blockIdx.y;
  if (j >= P) return;
  float S = 0.f;
  for (int c = 0; c < IC2; ++c) S += ps[((size_t)(s * IC2 + c)) * 2048 + j];
  v[s * P + j] += __logf(S);
}

// build-combine over ICB=200 chunks
__global__ void k_combineB(const float* __restrict__ ps, float* __restrict__ v) {
  int j = blockIdx.x * 256 + threadIdx.x;
  int s = blockIdx.y;
  if (j >= P) return;
  float S = 0.f;
  for (int c = 0; c < ICB; ++c) S += ps[((size_t)(s * ICB + c)) * 2048 + j];
  v[s * P + j] += __logf(S);
}

// theta[s,i,j] = Q*exp(-du-dv) -> bf16; fused fp32 mean -> thp
__global__ void __launch_bounds__(256) k_theta_mean(const unsigned short* __restrict__ Q,
    const float* __restrict__ du, const float* __restrict__ dv,
    unsigned short* __restrict__ th, float* __restrict__ thp) {
  int i = blockIdx.x, t = threadIdx.x;
  if (t >= 250) return;
  int j0 = t * 4;
  float4 acc = make_float4(0.f, 0.f, 0.f, 0.f);
  #pragma unroll
  for (int s = 0; s < NS; ++s) {
    float duo = du[s * P + i];
    ushort4 q4 = *(const ushort4*)(Q + ((size_t)s * P + i) * P + j0);
    float4 vv = *(const float4*)(dv + s * P + j0);
    float t0 = bf2f(q4.x) * __expf(-duo - vv.x);
    float t1 = bf2f(q4.y) * __expf(-duo - vv.y);
    float t2 = bf2f(q4.z) * __expf(-duo - vv.z);
    float t3 = bf2f(q4.w) * __expf(-duo - vv.w);
    *(ushort4*)(th + ((size_t)s * N_NODES + i) * N_NODES + j0) =
        make_ushort4(f2bf(t0), f2bf(t1), f2bf(t2), f2bf(t3));
    acc.x += t0; acc.y += t1; acc.z += t2; acc.w += t3;
  }
  acc.x *= 0.125f; acc.y *= 0.125f; acc.z *= 0.125f; acc.w *= 0.125f;
  *(float4*)(thp + (size_t)i * N_NODES + j0) = acc;
}

// fused reward on bf16 theta, XCD-affinity, NB=4 b-rows per block:
// one epackD read drives 4 FMA pairs (edge loop amortized 4x).
__global__ void __launch_bounds__(256) k_reward(const unsigned short* __restrict__ th,
    const int* __restrict__ startA, const int* __restrict__ partA,
    const int* __restrict__ epackD, float* __restrict__ matched) {
  __shared__ float xrow[NB][N_NODES];
  __shared__ float yrow[NB][N_NODES];
  int s = blockIdx.x & 7, bg = blockIdx.x >> 3;
  int b0 = bg * NB;
  int t = threadIdx.x;
  if (t < 250) {
    #pragma unroll
    for (int nb = 0; nb < NB; ++nb) {
      int b = b0 + nb;
      ushort4 x4 = ((const ushort4*)(th + ((size_t)s * N_NODES + b) * N_NODES))[t];
      ((float4*)xrow[nb])[t] = make_float4(bf2f(x4.x), bf2f(x4.y), bf2f(x4.z), bf2f(x4.w));
      float4 y4 = make_float4(0.f, 0.f, 0.f, 0.f);
      int e0 = startA[b], e1 = startA[b + 1];
      for (int q = e0; q < e1; ++q) {
        ushort4 v4 = ((const ushort4*)(th + ((size_t)s * N_NODES + partA[q]) * N_NODES))[t];
        y4.x += bf2f(v4.x); y4.y += bf2f(v4.y); y4.z += bf2f(v4.z); y4.w += bf2f(v4.w);
      }
      ((float4*)yrow[nb])[t] = y4;
    }
  }
  __syncthreads();
  float acc = 0.f;
  for (int m = t; m < N_EDGES; m += 256) {
    int pk = epackD[m];
    int d = pk >> 10, c = pk & 1023;
    #pragma unroll
    for (int nb = 0; nb < NB; ++nb)
      acc += yrow[nb][d] * xrow[nb][c];
  }
  float ssum = blockSum256(acc);
  if (t == 0) atomicAdd(matched + s, ssum);
}

__global__ void k_fin0(const float* __restrict__ matched, float* __restrict__ scal) {
  if (threadIdx.x == 0) {
    float accm = 0.f;
    for (int s = 0; s < NS; ++s) {
      float m = matched[s];
      float rv = m + (-1.0f) * ((16000.0f - m) + (16000.0f - m));
      accm += rv;
    }
    scal[0] = (accm / 8.0f) / 16000.0f;
  }
}

__global__ void k_fin1(const float* __restrict__ matched, float* __restrict__ scal,
                       float* __restrict__ out) {
  if (threadIdx.x == 0) {
    float accm = 0.f;
    for (int s = 0; s < NS; ++s) {
      float m = matched[s];
      float rv = m + (-1.0f) * ((16000.0f - m) + (16000.0f - m));
      accm += rv;
    }
    float r1 = (accm / 8.0f) / 16000.0f;
    float r0 = scal[0];
    int improved = (r1 > r0) ? 1 : 0;
    scal[1] = r1;
    scal[2] = (float)improved;
    float loss = -r0 - (improved ? r1 : 0.f);
    float cnt = improved ? 2.0f : 1.0f;
    out[(size_t)P * P] = loss / cnt;
  }
}

__global__ void k_out_sel(const float* __restrict__ laA, const float* __restrict__ laB,
                          const float* __restrict__ scal, float* __restrict__ out) {
  int q = blockIdx.x * 256 + threadIdx.x;
  if (q >= P * P / 4) return;
  const float* la = (scal[2] != 0.0f) ? laB : laA;
  int row = q / (P / 4);
  int jc = (q % (P / 4)) * 4;
  float4 vv = make_float4(0.f, 0.f, 0.f, 0.f);
  if (row < N_NODES && jc < N_NODES)
    vv = *(const float4*)(la + (size_t)row * N_NODES + jc);
  *(float4*)(out + (size_t)row * P + jc) = vv;
}

// ---------------- launch ----------------
extern "C" void kernel_launch(void* const* d_in, const int* in_sizes, int n_in,
                              void* d_out, int out_size, void* d_ws, size_t ws_size,
                              hipStream_t stream) {
  (void)in_sizes; (void)n_in; (void)out_size; (void)ws_size;
  const float* x_s = (const float*)d_in[0];
  const int*   e_s = (const int*)d_in[1];
  const float* x_t = (const float*)d_in[2];
  const int*   e_t = (const int*)d_in[3];
  const float* W1  = (const float*)d_in[4];
  const float* b1  = (const float*)d_in[5];
  const float* W2  = (const float*)d_in[6];
  const float* b2  = (const float*)d_in[7];
  float* out = (float*)d_out;

  // workspace layout
  unsigned short* Qbuf  = (unsigned short*)d_ws;   // 32,000,000 bf16 (64 MB)
  unsigned short* theta = Qbuf + 32000000;         //  8,000,000 bf16 (16 MB)
  float* laA   = (float*)(theta + 8000000);        //  1,000,000 f32
  float* laB   = laA + 1000000;
  float* thp   = laB + 1000000;
  float* h0    = thp + 1000000;                    //    512,000 (2 graphs)
  float* agg   = h0 + 512000;
  float* h1    = agg + 512000;
  float* h2    = h1 + 512000;
  float* hn    = h2 + 512000;
  float* uarr  = hn + 512000;                      //     16,000 (du)
  float* varr  = uarr + 16000;                     //     16,000 (dv)
  float* ps    = varr + 16000;                     //  3,276,800 (ICB*NS*2048)
  float* imp   = ps + 3276800;                     //      2,048
  float* matched = imp + 2048;
  float* scal  = matched + 16;
  int* cnt    = (int*)(scal + 16);                 // 1,024
  int* cursor = cnt + 1024;                        // 1,024
  int* ids    = cursor + 1024;                     // 16,000
  int* startA = ids + 16000;                       // 1,008
  int* startB = startA + 1008;                     // 1,008
  int* partA  = startB + 1008;                     // 16,000
  int* partB  = partA + 16000;                     // 16,000
  int* epackD = partB + 16000;                     // 16,000

  const int* keys[2]  = { e_s + N_EDGES, e_t + N_EDGES };
  const int* parts[2] = { e_s,           e_t           };
  int* outs_s[2] = { startA, startB };
  int* outs_p[2] = { partA,  partB  };
  for (int r = 0; r < 2; ++r) {
    hipMemsetAsync(cnt, 0, 2048 * sizeof(int), stream);
    k_hist<<<63, 256, 0, stream>>>(keys[r], cnt);
    k_scan<<<1, 1024, 0, stream>>>(cnt, outs_s[r]);
    k_scatter<<<63, 256, 0, stream>>>(keys[r], outs_s[r], cursor, ids);
    k_partfill<<<63, 256, 0, stream>>>(ids, parts[r], outs_p[r]);
  }
  k_packD<<<4, 256, 0, stream>>>(startB, partB, epackD);

  uint32_t k0 = 0u, k1 = 42u;
  uint32_t sub[2][2];
  for (int it = 0; it < 2; ++it) {
    uint32_t nk0, nk1, s0, s1;
    tf2x32(k0, k1, 0u, 0u, &nk0, &nk1);
    tf2x32(k0, k1, 0u, 1u, &s0, &s1);
    sub[it][0] = s0; sub[it][1] = s1;
    k0 = nk0; k1 = nk1;
  }

  for (int it = 0; it < 2; ++it) {
    if (it == 0) {
      k_ones<<<8, 256, 0, stream>>>(imp);
    } else {
      k_rowsum<<<N_NODES, 256, 0, stream>>>(thp, imp);
      hipMemsetAsync(imp + 1024, 0, 1024 * sizeof(float), stream);
      k_colsum<<<dim3(4, 8), 256, 0, stream>>>(thp, imp);
    }
    k_scale_b<<<dim3(N_NODES, 2), 256, 0, stream>>>(x_s, x_t, imp, h0);
    k_agg_b<<<dim3(N_NODES, 2), 256, 0, stream>>>(h0, startA, partA, agg);
    k_lin_b<<<dim3(63, 4, 2), 256, 0, stream>>>(h0, agg, W1, b1, h1, 1);
    k_agg_b<<<dim3(N_NODES, 2), 256, 0, stream>>>(h1, startA, partA, agg);
    k_lin_b<<<dim3(63, 4, 2), 256, 0, stream>>>(h1, agg, W2, b2, h2, 0);
    k_norm_b<<<dim3(N_NODES, 2), 256, 0, stream>>>(h2, hn);
    float* la = it ? laB : laA;
    k_gemm50<<<dim3(16, 16), 256, 0, stream>>>(hn, hn + 256000, la);

    // sinkhorn on bf16 Q: du/dv potentials start at 0
    hipMemsetAsync(uarr, 0, 2 * NS * P * sizeof(float), stream);  // du + dv
    k_build<<<dim3(ICB, NS), 256, 0, stream>>>(la, Qbuf, ps,
                                               sub[it][0], sub[it][1]);
    k_combineB<<<dim3(8, NS), 256, 0, stream>>>(ps, varr);
    for (int k = 0; k < 9; ++k) {
      k_fused<<<dim3(IC2, NS), 256, 0, stream>>>(Qbuf, varr, uarr, ps);
      k_combine<<<dim3(8, NS), 256, 0, stream>>>(ps, varr);
    }

    k_theta_mean<<<N_NODES, 256, 0, stream>>>(Qbuf, uarr, varr, theta, thp);
    hipMemsetAsync(matched, 0, NS * 4, stream);
    k_reward<<<(N_NODES / NB) * 8, 256, 0, stream>>>(theta, startA, partA,
                                                     epackD, matched);
    if (it == 0) k_fin0<<<1, 64, 0, stream>>>(matched, scal);
    else         k_fin1<<<1, 64, 0, stream>>>(matched, scal, out);
  }
  k_out_sel<<<3907, 256, 0, stream>>>(laA, laB, scal, out);
}

// Round 15
// 1176.283 us; speedup vs baseline: 1.5657x; 1.0026x over previous
//
#include <hip/hip_runtime.h>
#include <stdint.h>
#include <math.h>

#define N_NODES 1000
#define DIM 256
#define N_EDGES 16000
#define NS 8            // gumbel samples
#define P 2000          // padded sinkhorn size
#define IC2 100         // row chunks for k_fused (R8 measured config)
#define RPC (P / IC2)   // rows per fused chunk = 20
#define ICB 200         // row chunks for k_build (measured: 160->135us)
#define RPB (P / ICB)   // rows per build chunk = 10
#define GR 5            // rows per register-group in k_fused
#define NB 4            // b-rows per reward block (edge-loop amortization)

// ---------------- bf16 helpers (RNE) ----------------
__device__ inline unsigned short f2bf(float f) {
  uint32_t x = __float_as_uint(f);
  uint32_t r = (x + 0x7FFFu + ((x >> 16) & 1u)) >> 16;
  return (unsigned short)r;
}
__device__ inline float bf2f(unsigned short u) {
  return __uint_as_float(((uint32_t)u) << 16);
}

// ---------------- Threefry-2x32 (exact JAX) ----------------
__host__ __device__ inline void tf2x32(uint32_t k0, uint32_t k1,
                                       uint32_t x0, uint32_t x1,
                                       uint32_t* o0, uint32_t* o1) {
  const uint32_t ks2 = k0 ^ k1 ^ 0x1BD11BDAu;
  uint32_t a = x0 + k0, b = x1 + k1;
#define RL(v, d) (((v) << (d)) | ((v) >> (32 - (d))))
#define RND(r) { a += b; b = RL(b, r); b ^= a; }
  RND(13) RND(15) RND(26) RND(6)
  a += k1;  b += ks2 + 1u;
  RND(17) RND(29) RND(16) RND(24)
  a += ks2; b += k0 + 2u;
  RND(13) RND(15) RND(26) RND(6)
  a += k0;  b += k1 + 3u;
  RND(17) RND(29) RND(16) RND(24)
  a += k1;  b += ks2 + 4u;
  RND(13) RND(15) RND(26) RND(6)
  a += ks2; b += k0 + 5u;
#undef RND
#undef RL
  *o0 = a; *o1 = b;
}

__device__ inline float gumbel_from_idx(uint32_t k0, uint32_t k1, uint32_t idx) {
  uint32_t b0, b1;
  tf2x32(k0, k1, 0u, idx, &b0, &b1);
  uint32_t bits = b0 ^ b1;
  float u = __uint_as_float((bits >> 9) | 0x3f800000u) - 1.0f;
  return -__logf(-__logf(u + 1e-20f) + 1e-20f);
}

// ---------------- block reductions (blockDim==256) ----------------
__device__ inline float blockSum256(float v) {
  __shared__ float sm[4];
  #pragma unroll
  for (int off = 32; off; off >>= 1) v += __shfl_down(v, off, 64);
  if ((threadIdx.x & 63) == 0) sm[threadIdx.x >> 6] = v;
  __syncthreads();
  float r = (sm[0] + sm[1]) + (sm[2] + sm[3]);
  __syncthreads();
  return r;
}
__device__ inline float blockMax256(float v) {
  __shared__ float sm[4];
  #pragma unroll
  for (int off = 32; off; off >>= 1) v = fmaxf(v, __shfl_down(v, off, 64));
  if ((threadIdx.x & 63) == 0) sm[threadIdx.x >> 6] = v;
  __syncthreads();
  float r = fmaxf(fmaxf(sm[0], sm[1]), fmaxf(sm[2], sm[3]));
  __syncthreads();
  return r;
}

// ---------------- CSR build ----------------
__global__ void k_hist(const int* __restrict__ key, int* __restrict__ cnt) {
  int k = blockIdx.x * 256 + threadIdx.x;
  if (k < N_EDGES) atomicAdd(&cnt[key[k]], 1);
}
__global__ void k_scan(const int* __restrict__ cnt, int* __restrict__ start) {
  __shared__ int sm[1024];
  int t = threadIdx.x;
  sm[t] = (t < N_NODES) ? cnt[t] : 0;
  __syncthreads();
  for (int off = 1; off < 1024; off <<= 1) {
    int v = (t >= off) ? sm[t - off] : 0;
    __syncthreads();
    sm[t] += v;
    __syncthreads();
  }
  if (t < N_NODES) start[t + 1] = sm[t];
  if (t == 0) start[0] = 0;
}
__global__ void k_scatter(const int* __restrict__ key, const int* __restrict__ start,
                          int* __restrict__ cursor, int* __restrict__ ids) {
  int k = blockIdx.x * 256 + threadIdx.x;
  if (k < N_EDGES) {
    int c = key[k];
    int slot = start[c] + atomicAdd(&cursor[c], 1);
    ids[slot] = k;
  }
}
__global__ void k_partfill(const int* __restrict__ ids, const int* __restrict__ pv,
                           int* __restrict__ part) {
  int s = blockIdx.x * 256 + threadIdx.x;
  if (s < N_EDGES) part[s] = pv[ids[s]];
}
__global__ void k_packD(const int* __restrict__ startB, const int* __restrict__ partB,
                        int* __restrict__ epackD) {
  int d = blockIdx.x * 256 + threadIdx.x;
  if (d >= N_NODES) return;
  int e0 = startB[d], e1 = startB[d + 1];
  for (int q = e0; q < e1; ++q) epackD[q] = (d << 10) | partB[q];
}

// ---------------- small kernels ----------------
__global__ void k_ones(float* imp) {
  int t = blockIdx.x * 256 + threadIdx.x;
  if (t < 2048) imp[t] = 1.0f;
}

__global__ void k_rowsum(const float* __restrict__ thp, float* __restrict__ imp) {
  int i = blockIdx.x;
  float a = 0.f;
  for (int j = threadIdx.x; j < N_NODES; j += 256) a += thp[(size_t)i * N_NODES + j];
  float s = blockSum256(a);
  if (threadIdx.x == 0) imp[i] = s;
}

__global__ void k_colsum(const float* __restrict__ thp, float* __restrict__ imp) {
  int j = blockIdx.x * 256 + threadIdx.x;
  if (j >= N_NODES) return;
  int r0 = blockIdx.y * 125;
  float a = 0.f;
  for (int i = r0; i < r0 + 125; ++i) a += thp[(size_t)i * N_NODES + j];
  atomicAdd(&imp[1024 + j], a);
}

__global__ void k_scale_b(const float* __restrict__ xs, const float* __restrict__ xt,
                          const float* __restrict__ imp, float* __restrict__ h) {
  int g = blockIdx.y, i = blockIdx.x, d = threadIdx.x;
  const float* x = g ? xt : xs;
  h[(size_t)g * 256000 + i * DIM + d] = x[i * DIM + d] * imp[g * 1024 + i];
}

__global__ void k_agg_b(const float* __restrict__ h, const int* __restrict__ start,
                        const int* __restrict__ part, float* __restrict__ agg) {
  int g = blockIdx.y, i = blockIdx.x, d = threadIdx.x;
  const int* st = start + g * 1008;
  const int* pt = part + g * 16000;
  const float* hh = h + (size_t)g * 256000;
  int e0 = st[i], e1 = st[i + 1];
  float a = 0.f;
  for (int q = e0; q < e1; ++q) a += hh[(size_t)pt[q] * DIM + d];
  agg[(size_t)g * 256000 + i * DIM + d] = a;
}

__global__ void __launch_bounds__(256) k_lin_b(const float* __restrict__ h_,
    const float* __restrict__ agg_, const float* __restrict__ Wm,
    const float* __restrict__ bias, float* __restrict__ out_, int relu) {
  __shared__ float As[16][64];
  __shared__ float Ws[64][64];
  int g = blockIdx.z;
  const float* h   = h_   + (size_t)g * 256000;
  const float* agg = agg_ + (size_t)g * 256000;
  float* out       = out_ + (size_t)g * 256000;
  int tx = threadIdx.x & 63;
  int ty = threadIdx.x >> 6;
  int row0 = blockIdx.x * 16;
  int col0 = blockIdx.y * 64;
  float acc[4] = {0.f, 0.f, 0.f, 0.f};
  for (int kc = 0; kc < DIM; kc += 64) {
    for (int t = threadIdx.x; t < 16 * 64; t += 256) {
      int r = t >> 6, c = t & 63;
      int gr = row0 + r;
      As[r][c] = (gr < N_NODES) ? (h[gr * DIM + kc + c] + agg[gr * DIM + kc + c]) : 0.f;
    }
    for (int t = threadIdx.x; t < 64 * 64; t += 256) {
      int r = t >> 6, c = t & 63;
      Ws[r][c] = Wm[(kc + r) * DIM + col0 + c];
    }
    __syncthreads();
    #pragma unroll 8
    for (int kk = 0; kk < 64; ++kk) {
      float w = Ws[kk][tx];
      acc[0] += As[ty][kk] * w;
      acc[1] += As[ty + 4][kk] * w;
      acc[2] += As[ty + 8][kk] * w;
      acc[3] += As[ty + 12][kk] * w;
    }
    __syncthreads();
  }
  int col = col0 + tx;
  float bv = bias[col];
  #pragma unroll
  for (int r = 0; r < 4; ++r) {
    int gr = row0 + ty + r * 4;
    if (gr < N_NODES) {
      float vv = acc[r] + bv;
      if (relu) vv = fmaxf(vv, 0.f);
      out[gr * DIM + col] = vv;
    }
  }
}

__global__ void k_norm_b(const float* __restrict__ h, float* __restrict__ out) {
  int g = blockIdx.y, i = blockIdx.x;
  float x = h[(size_t)g * 256000 + i * DIM + threadIdx.x];
  float ss = blockSum256(x * x);
  float nrm = sqrtf(ss);
  out[(size_t)g * 256000 + i * DIM + threadIdx.x] = x / nrm;
}

__global__ void __launch_bounds__(256) k_gemm50(const float* __restrict__ A,
    const float* __restrict__ B, float* __restrict__ C) {
  __shared__ float As[64][33];
  __shared__ float Bs[64][33];
  int tr = threadIdx.x >> 4;
  int tc = threadIdx.x & 15;
  int i0 = blockIdx.x * 64, j0 = blockIdx.y * 64;
  float acc[4][4] = {};
  for (int kc = 0; kc < DIM; kc += 32) {
    for (int t = threadIdx.x; t < 64 * 32; t += 256) {
      int r = t >> 5, c = t & 31;
      int gi = i0 + r; As[r][c] = (gi < N_NODES) ? A[gi * DIM + kc + c] : 0.f;
      int gj = j0 + r; Bs[r][c] = (gj < N_NODES) ? B[gj * DIM + kc + c] : 0.f;
    }
    __syncthreads();
    for (int kk = 0; kk < 32; ++kk) {
      float a[4], b[4];
      #pragma unroll
      for (int q = 0; q < 4; ++q) a[q] = As[tr * 4 + q][kk];
      #pragma unroll
      for (int q = 0; q < 4; ++q) b[q] = Bs[tc * 4 + q][kk];
      #pragma unroll
      for (int r = 0; r < 4; ++r)
        #pragma unroll
        for (int c = 0; c < 4; ++c) acc[r][c] += a[r] * b[c];
    }
    __syncthreads();
  }
  for (int r = 0; r < 4; ++r) {
    int gi = i0 + tr * 4 + r;
    if (gi >= N_NODES) continue;
    for (int c = 0; c < 4; ++c) {
      int gj = j0 + tc * 4 + c;
      if (gj < N_NODES) C[(size_t)gi * N_NODES + gj] = 50.0f * acc[r][c];
    }
  }
}

// build: Q = exp(b - u1) stored bf16 (row-normalized residual, in [0,1]);
// v1 col-partials from unrounded values.
__global__ void __launch_bounds__(256) k_build(const float* __restrict__ la,
    unsigned short* __restrict__ Q, float* __restrict__ ps,
    uint32_t k0, uint32_t k1) {
  int ic = blockIdx.x, s = blockIdx.y;
  int t = threadIdx.x;
  int j0 = t * 8;
  bool act = (j0 < P);
  float acc[8] = {0.f,0.f,0.f,0.f,0.f,0.f,0.f,0.f};
  for (int r = 0; r < RPB; ++r) {
    int i = ic * RPB + r;
    float bv[8];
    float lmax = -INFINITY;
    if (act) {
      uint32_t idxbase = (uint32_t)((s * P + i) * P + j0);
      #pragma unroll
      for (int q = 0; q < 8; ++q) {
        int j = j0 + q;
        float g = gumbel_from_idx(k0, k1, idxbase + (uint32_t)q);
        float lav = (i < N_NODES && j < N_NODES) ? la[(size_t)i * N_NODES + j] : 0.0f;
        bv[q] = (lav + g) * 10.0f;
        lmax = fmaxf(lmax, bv[q]);
      }
    }
    float M = blockMax256(lmax);
    float e[8];
    float ls = 0.f;
    if (act) {
      #pragma unroll
      for (int q = 0; q < 8; ++q) { e[q] = __expf(bv[q] - M); ls += e[q]; }
    }
    float S = blockSum256(ls);
    if (act) {
      float rs = 1.0f / S;
      unsigned short q8[8];
      #pragma unroll
      for (int q = 0; q < 8; ++q) {
        float val = e[q] * rs;
        acc[q] += val;
        q8[q] = f2bf(val);
      }
      ushort4* qp = (ushort4*)(Q + ((size_t)s * P + i) * P + j0);
      qp[0] = make_ushort4(q8[0], q8[1], q8[2], q8[3]);
      qp[1] = make_ushort4(q8[4], q8[5], q8[6], q8[7]);
    }
  }
  if (act) {
    float* pp = ps + ((size_t)(s * ICB + ic)) * 2048 + j0;
    ((float4*)pp)[0] = make_float4(acc[0], acc[1], acc[2], acc[3]);
    ((float4*)pp)[1] = make_float4(acc[4], acc[5], acc[6], acc[7]);
  }
}

// fused sinkhorn pass on bf16 Q: e = Q*exp(-du_i)*ev_j (ev precomputed).
__global__ void __launch_bounds__(256) k_fused(const unsigned short* __restrict__ Q,
    const float* __restrict__ evbuf, float* __restrict__ du, float* __restrict__ ps) {
  int ic = blockIdx.x, s = blockIdx.y;
  int t = threadIdx.x;
  int lane = t & 63, wave = t >> 6;
  int j0 = t * 8;
  bool act = (j0 < P);
  __shared__ float pr[GR][4];
  __shared__ float Sr[GR];
  float ev[8];
  if (act) {
    float4 v0 = *(const float4*)(evbuf + s * P + j0);
    float4 v1 = *(const float4*)(evbuf + s * P + j0 + 4);
    ev[0] = v0.x; ev[1] = v0.y; ev[2] = v0.z; ev[3] = v0.w;
    ev[4] = v1.x; ev[5] = v1.y; ev[6] = v1.z; ev[7] = v1.w;
  }
  float acc[8] = {0.f,0.f,0.f,0.f,0.f,0.f,0.f,0.f};
  for (int g = 0; g < RPC / GR; ++g) {
    float e[GR][8];
    #pragma unroll
    for (int r = 0; r < GR; ++r) {
      int i = ic * RPC + g * GR + r;
      float edu = __expf(-du[s * P + i]);
      float ls = 0.f;
      if (act) {
        const unsigned short* qrow = Q + ((size_t)s * P + i) * P + j0;
        ushort4 a = *(const ushort4*)qrow;
        ushort4 b = *(const ushort4*)(qrow + 4);
        e[r][0] = bf2f(a.x) * edu * ev[0];
        e[r][1] = bf2f(a.y) * edu * ev[1];
        e[r][2] = bf2f(a.z) * edu * ev[2];
        e[r][3] = bf2f(a.w) * edu * ev[3];
        e[r][4] = bf2f(b.x) * edu * ev[4];
        e[r][5] = bf2f(b.y) * edu * ev[5];
        e[r][6] = bf2f(b.z) * edu * ev[6];
        e[r][7] = bf2f(b.w) * edu * ev[7];
        #pragma unroll
        for (int q = 0; q < 8; ++q) ls += e[r][q];
      }
      #pragma unroll
      for (int off = 32; off; off >>= 1) ls += __shfl_down(ls, off, 64);
      if (lane == 0) pr[r][wave] = ls;
    }
    __syncthreads();
    if (t < GR) {
      float S = (pr[t][0] + pr[t][1]) + (pr[t][2] + pr[t][3]);
      Sr[t] = S;
      du[s * P + ic * RPC + g * GR + t] += __logf(S);
    }
    __syncthreads();
    if (act) {
      #pragma unroll
      for (int r = 0; r < GR; ++r) {
        float rs = 1.0f / Sr[r];
        #pragma unroll
        for (int q = 0; q < 8; ++q) acc[q] += e[r][q] * rs;
      }
    }
  }
  if (act) {
    float* pp = ps + ((size_t)(s * IC2 + ic)) * 2048 + j0;
    ((float4*)pp)[0] = make_float4(acc[0], acc[1], acc[2], acc[3]);
    ((float4*)pp)[1] = make_float4(acc[4], acc[5], acc[6], acc[7]);
  }
}

// dv_new = dv_old + log(sum_c ps); also emit evbuf = exp(-dv_new)
template<int NCH>
__global__ void k_combineT(const float* __restrict__ ps, float* __restrict__ v,
                           float* __restrict__ evbuf) {
  int j = blockIdx.x * 256 + threadIdx.x;
  int s = blockIdx.y;
  if (j >= P) return;
  float S = 0.f;
  for (int c = 0; c < NCH; ++c) S += ps[((size_t)(s * NCH + c)) * 2048 + j];
  float nv = v[s * P + j] + __logf(S);
  v[s * P + j] = nv;
  evbuf[s * P + j] = __expf(-nv);
}

// theta[s,i,j] = Q*edu*ev -> bf16; optional fused fp32 mean -> thp
template<int DO_MEAN>
__global__ void __launch_bounds__(256) k_theta_mean(const unsigned short* __restrict__ Q,
    const float* __restrict__ du, const float* __restrict__ evbuf,
    unsigned short* __restrict__ th, float* __restrict__ thp) {
  int i = blockIdx.x, t = threadIdx.x;
  if (t >= 250) return;
  int j0 = t * 4;
  float4 acc = make_float4(0.f, 0.f, 0.f, 0.f);
  #pragma unroll
  for (int s = 0; s < NS; ++s) {
    float edu = __expf(-du[s * P + i]);
    ushort4 q4 = *(const ushort4*)(Q + ((size_t)s * P + i) * P + j0);
    float4 vv = *(const float4*)(evbuf + s * P + j0);
    float t0 = bf2f(q4.x) * edu * vv.x;
    float t1 = bf2f(q4.y) * edu * vv.y;
    float t2 = bf2f(q4.z) * edu * vv.z;
    float t3 = bf2f(q4.w) * edu * vv.w;
    *(ushort4*)(th + ((size_t)s * N_NODES + i) * N_NODES + j0) =
        make_ushort4(f2bf(t0), f2bf(t1), f2bf(t2), f2bf(t3));
    if (DO_MEAN) { acc.x += t0; acc.y += t1; acc.z += t2; acc.w += t3; }
  }
  if (DO_MEAN) {
    acc.x *= 0.125f; acc.y *= 0.125f; acc.z *= 0.125f; acc.w *= 0.125f;
    *(float4*)(thp + (size_t)i * N_NODES + j0) = acc;
  }
}

// fused reward on bf16 theta, XCD-affinity, NB=4 b-rows per block
__global__ void __launch_bounds__(256) k_reward(const unsigned short* __restrict__ th,
    const int* __restrict__ startA, const int* __restrict__ partA,
    const int* __restrict__ epackD, float* __restrict__ matched) {
  __shared__ float xrow[NB][N_NODES];
  __shared__ float yrow[NB][N_NODES];
  int s = blockIdx.x & 7, bg = blockIdx.x >> 3;
  int b0 = bg * NB;
  int t = threadIdx.x;
  if (t < 250) {
    #pragma unroll
    for (int nb = 0; nb < NB; ++nb) {
      int b = b0 + nb;
      ushort4 x4 = ((const ushort4*)(th + ((size_t)s * N_NODES + b) * N_NODES))[t];
      ((float4*)xrow[nb])[t] = make_float4(bf2f(x4.x), bf2f(x4.y), bf2f(x4.z), bf2f(x4.w));
      float4 y4 = make_float4(0.f, 0.f, 0.f, 0.f);
      int e0 = startA[b], e1 = startA[b + 1];
      for (int q = e0; q < e1; ++q) {
        ushort4 v4 = ((const ushort4*)(th + ((size_t)s * N_NODES + partA[q]) * N_NODES))[t];
        y4.x += bf2f(v4.x); y4.y += bf2f(v4.y); y4.z += bf2f(v4.z); y4.w += bf2f(v4.w);
      }
      ((float4*)yrow[nb])[t] = y4;
    }
  }
  __syncthreads();
  float acc = 0.f;
  for (int m = t; m < N_EDGES; m += 256) {
    int pk = epackD[m];
    int d = pk >> 10, c = pk & 1023;
    #pragma unroll
    for (int nb = 0; nb < NB; ++nb)
      acc += yrow[nb][d] * xrow[nb][c];
  }
  float ssum = blockSum256(acc);
  if (t == 0) atomicAdd(matched + s, ssum);
}

__global__ void k_fin0(const float* __restrict__ matched, float* __restrict__ scal) {
  if (threadIdx.x == 0) {
    float accm = 0.f;
    for (int s = 0; s < NS; ++s) {
      float m = matched[s];
      float rv = m + (-1.0f) * ((16000.0f - m) + (16000.0f - m));
      accm += rv;
    }
    scal[0] = (accm / 8.0f) / 16000.0f;
  }
}

__global__ void k_fin1(const float* __restrict__ matched, float* __restrict__ scal,
                       float* __restrict__ out) {
  if (threadIdx.x == 0) {
    float accm = 0.f;
    for (int s = 0; s < NS; ++s) {
      float m = matched[s];
      float rv = m + (-1.0f) * ((16000.0f - m) + (16000.0f - m));
      accm += rv;
    }
    float r1 = (accm / 8.0f) / 16000.0f;
    float r0 = scal[0];
    int improved = (r1 > r0) ? 1 : 0;
    scal[1] = r1;
    scal[2] = (float)improved;
    float loss = -r0 - (improved ? r1 : 0.f);
    float cnt = improved ? 2.0f : 1.0f;
    out[(size_t)P * P] = loss / cnt;
  }
}

__global__ void k_out_sel(const float* __restrict__ laA, const float* __restrict__ laB,
                          const float* __restrict__ scal, float* __restrict__ out) {
  int q = blockIdx.x * 256 + threadIdx.x;
  if (q >= P * P / 4) return;
  const float* la = (scal[2] != 0.0f) ? laB : laA;
  int row = q / (P / 4);
  int jc = (q % (P / 4)) * 4;
  float4 vv = make_float4(0.f, 0.f, 0.f, 0.f);
  if (row < N_NODES && jc < N_NODES)
    vv = *(const float4*)(la + (size_t)row * N_NODES + jc);
  *(float4*)(out + (size_t)row * P + jc) = vv;
}

// ---------------- launch ----------------
extern "C" void kernel_launch(void* const* d_in, const int* in_sizes, int n_in,
                              void* d_out, int out_size, void* d_ws, size_t ws_size,
                              hipStream_t stream) {
  (void)in_sizes; (void)n_in; (void)out_size; (void)ws_size;
  const float* x_s = (const float*)d_in[0];
  const int*   e_s = (const int*)d_in[1];
  const float* x_t = (const float*)d_in[2];
  const int*   e_t = (const int*)d_in[3];
  const float* W1  = (const float*)d_in[4];
  const float* b1  = (const float*)d_in[5];
  const float* W2  = (const float*)d_in[6];
  const float* b2  = (const float*)d_in[7];
  float* out = (float*)d_out;

  // workspace layout
  unsigned short* Qbuf  = (unsigned short*)d_ws;   // 32,000,000 bf16 (64 MB)
  unsigned short* theta = Qbuf + 32000000;         //  8,000,000 bf16 (16 MB)
  float* laA   = (float*)(theta + 8000000);        //  1,000,000 f32
  float* laB   = laA + 1000000;
  float* thp   = laB + 1000000;
  float* h0    = thp + 1000000;                    //    512,000 (2 graphs)
  float* agg   = h0 + 512000;
  float* h1    = agg + 512000;
  float* h2    = h1 + 512000;
  float* hn    = h2 + 512000;
  float* uarr  = hn + 512000;                      //     16,000 (du)
  float* varr  = uarr + 16000;                     //     16,000 (dv)
  float* evbuf = varr + 16000;                     //     16,000 (exp(-dv))
  float* ps    = evbuf + 16000;                    //  3,276,800 (ICB*NS*2048)
  float* imp   = ps + 3276800;                     //      2,048
  float* matched = imp + 2048;
  float* scal  = matched + 16;
  int* cnt    = (int*)(scal + 16);                 // 1,024
  int* cursor = cnt + 1024;                        // 1,024
  int* ids    = cursor + 1024;                     // 16,000
  int* startA = ids + 16000;                       // 1,008
  int* startB = startA + 1008;                     // 1,008
  int* partA  = startB + 1008;                     // 16,000
  int* partB  = partA + 16000;                     // 16,000
  int* epackD = partB + 16000;                     // 16,000

  const int* keys[2]  = { e_s + N_EDGES, e_t + N_EDGES };
  const int* parts[2] = { e_s,           e_t           };
  int* outs_s[2] = { startA, startB };
  int* outs_p[2] = { partA,  partB  };
  for (int r = 0; r < 2; ++r) {
    hipMemsetAsync(cnt, 0, 2048 * sizeof(int), stream);
    k_hist<<<63, 256, 0, stream>>>(keys[r], cnt);
    k_scan<<<1, 1024, 0, stream>>>(cnt, outs_s[r]);
    k_scatter<<<63, 256, 0, stream>>>(keys[r], outs_s[r], cursor, ids);
    k_partfill<<<63, 256, 0, stream>>>(ids, parts[r], outs_p[r]);
  }
  k_packD<<<4, 256, 0, stream>>>(startB, partB, epackD);

  uint32_t k0 = 0u, k1 = 42u;
  uint32_t sub[2][2];
  for (int it = 0; it < 2; ++it) {
    uint32_t nk0, nk1, s0, s1;
    tf2x32(k0, k1, 0u, 0u, &nk0, &nk1);
    tf2x32(k0, k1, 0u, 1u, &s0, &s1);
    sub[it][0] = s0; sub[it][1] = s1;
    k0 = nk0; k1 = nk1;
  }

  for (int it = 0; it < 2; ++it) {
    if (it == 0) {
      k_ones<<<8, 256, 0, stream>>>(imp);
    } else {
      k_rowsum<<<N_NODES, 256, 0, stream>>>(thp, imp);
      hipMemsetAsync(imp + 1024, 0, 1024 * sizeof(float), stream);
      k_colsum<<<dim3(4, 8), 256, 0, stream>>>(thp, imp);
    }
    k_scale_b<<<dim3(N_NODES, 2), 256, 0, stream>>>(x_s, x_t, imp, h0);
    k_agg_b<<<dim3(N_NODES, 2), 256, 0, stream>>>(h0, startA, partA, agg);
    k_lin_b<<<dim3(63, 4, 2), 256, 0, stream>>>(h0, agg, W1, b1, h1, 1);
    k_agg_b<<<dim3(N_NODES, 2), 256, 0, stream>>>(h1, startA, partA, agg);
    k_lin_b<<<dim3(63, 4, 2), 256, 0, stream>>>(h1, agg, W2, b2, h2, 0);
    k_norm_b<<<dim3(N_NODES, 2), 256, 0, stream>>>(h2, hn);
    float* la = it ? laB : laA;
    k_gemm50<<<dim3(16, 16), 256, 0, stream>>>(hn, hn + 256000, la);

    // sinkhorn on bf16 Q: du/dv potentials start at 0
    hipMemsetAsync(uarr, 0, 2 * NS * P * sizeof(float), stream);  // du + dv
    k_build<<<dim3(ICB, NS), 256, 0, stream>>>(la, Qbuf, ps,
                                               sub[it][0], sub[it][1]);
    k_combineT<ICB><<<dim3(8, NS), 256, 0, stream>>>(ps, varr, evbuf);
    for (int k = 0; k < 9; ++k) {
      k_fused<<<dim3(IC2, NS), 256, 0, stream>>>(Qbuf, evbuf, uarr, ps);
      k_combineT<IC2><<<dim3(8, NS), 256, 0, stream>>>(ps, varr, evbuf);
    }

    if (it == 0)
      k_theta_mean<1><<<N_NODES, 256, 0, stream>>>(Qbuf, uarr, evbuf, theta, thp);
    else
      k_theta_mean<0><<<N_NODES, 256, 0, stream>>>(Qbuf, uarr, evbuf, theta, thp);
    hipMemsetAsync(matched, 0, NS * 4, stream);
    k_reward<<<(N_NODES / NB) * 8, 256, 0, stream>>>(theta, startA, partA,
                                                     epackD, matched);
    if (it == 0) k_fin0<<<1, 64, 0, stream>>>(matched, scal);
    else         k_fin1<<<1, 64, 0, stream>>>(matched, scal, out);
  }
  k_out_sel<<<3907, 256, 0, stream>>>(laA, laB, scal, out);
}

// Round 16
// 1157.824 us; speedup vs baseline: 1.5906x; 1.0159x over previous
//
#include <hip/hip_runtime.h>
#include <stdint.h>
#include <math.h>

#define N_NODES 1000
#define DIM 256
#define N_EDGES 16000
#define NS 8            // gumbel samples
#define P 2000          // padded sinkhorn size
#define IC2 100         // row chunks for k_fused (R8 measured config)
#define RPC (P / IC2)   // rows per fused chunk = 20
#define ICB 400         // row chunks for k_build (occupancy lever: 3200 blocks)
#define RPB (P / ICB)   // rows per build chunk = 5
#define GR 5            // rows per register-group in k_fused
#define NB 4            // b-rows per reward block (edge-loop amortization)

// ---------------- bf16 helpers (RNE) ----------------
__device__ inline unsigned short f2bf(float f) {
  uint32_t x = __float_as_uint(f);
  uint32_t r = (x + 0x7FFFu + ((x >> 16) & 1u)) >> 16;
  return (unsigned short)r;
}
__device__ inline float bf2f(unsigned short u) {
  return __uint_as_float(((uint32_t)u) << 16);
}

// ---------------- Threefry-2x32 (exact JAX) ----------------
__host__ __device__ inline void tf2x32(uint32_t k0, uint32_t k1,
                                       uint32_t x0, uint32_t x1,
                                       uint32_t* o0, uint32_t* o1) {
  const uint32_t ks2 = k0 ^ k1 ^ 0x1BD11BDAu;
  uint32_t a = x0 + k0, b = x1 + k1;
#define RL(v, d) (((v) << (d)) | ((v) >> (32 - (d))))
#define RND(r) { a += b; b = RL(b, r); b ^= a; }
  RND(13) RND(15) RND(26) RND(6)
  a += k1;  b += ks2 + 1u;
  RND(17) RND(29) RND(16) RND(24)
  a += ks2; b += k0 + 2u;
  RND(13) RND(15) RND(26) RND(6)
  a += k0;  b += k1 + 3u;
  RND(17) RND(29) RND(16) RND(24)
  a += k1;  b += ks2 + 4u;
  RND(13) RND(15) RND(26) RND(6)
  a += ks2; b += k0 + 5u;
#undef RND
#undef RL
  *o0 = a; *o1 = b;
}

__device__ inline float gumbel_from_idx(uint32_t k0, uint32_t k1, uint32_t idx) {
  uint32_t b0, b1;
  tf2x32(k0, k1, 0u, idx, &b0, &b1);
  uint32_t bits = b0 ^ b1;
  float u = __uint_as_float((bits >> 9) | 0x3f800000u) - 1.0f;
  return -__logf(-__logf(u + 1e-20f) + 1e-20f);
}

// ---------------- block reductions (blockDim==256) ----------------
__device__ inline float blockSum256(float v) {
  __shared__ float sm[4];
  #pragma unroll
  for (int off = 32; off; off >>= 1) v += __shfl_down(v, off, 64);
  if ((threadIdx.x & 63) == 0) sm[threadIdx.x >> 6] = v;
  __syncthreads();
  float r = (sm[0] + sm[1]) + (sm[2] + sm[3]);
  __syncthreads();
  return r;
}
__device__ inline float blockMax256(float v) {
  __shared__ float sm[4];
  #pragma unroll
  for (int off = 32; off; off >>= 1) v = fmaxf(v, __shfl_down(v, off, 64));
  if ((threadIdx.x & 63) == 0) sm[threadIdx.x >> 6] = v;
  __syncthreads();
  float r = fmaxf(fmaxf(sm[0], sm[1]), fmaxf(sm[2], sm[3]));
  __syncthreads();
  return r;
}

// ---------------- CSR build ----------------
__global__ void k_hist(const int* __restrict__ key, int* __restrict__ cnt) {
  int k = blockIdx.x * 256 + threadIdx.x;
  if (k < N_EDGES) atomicAdd(&cnt[key[k]], 1);
}
__global__ void k_scan(const int* __restrict__ cnt, int* __restrict__ start) {
  __shared__ int sm[1024];
  int t = threadIdx.x;
  sm[t] = (t < N_NODES) ? cnt[t] : 0;
  __syncthreads();
  for (int off = 1; off < 1024; off <<= 1) {
    int v = (t >= off) ? sm[t - off] : 0;
    __syncthreads();
    sm[t] += v;
    __syncthreads();
  }
  if (t < N_NODES) start[t + 1] = sm[t];
  if (t == 0) start[0] = 0;
}
__global__ void k_scatter(const int* __restrict__ key, const int* __restrict__ start,
                          int* __restrict__ cursor, int* __restrict__ ids) {
  int k = blockIdx.x * 256 + threadIdx.x;
  if (k < N_EDGES) {
    int c = key[k];
    int slot = start[c] + atomicAdd(&cursor[c], 1);
    ids[slot] = k;
  }
}
__global__ void k_partfill(const int* __restrict__ ids, const int* __restrict__ pv,
                           int* __restrict__ part) {
  int s = blockIdx.x * 256 + threadIdx.x;
  if (s < N_EDGES) part[s] = pv[ids[s]];
}
__global__ void k_packD(const int* __restrict__ startB, const int* __restrict__ partB,
                        int* __restrict__ epackD) {
  int d = blockIdx.x * 256 + threadIdx.x;
  if (d >= N_NODES) return;
  int e0 = startB[d], e1 = startB[d + 1];
  for (int q = e0; q < e1; ++q) epackD[q] = (d << 10) | partB[q];
}

// ---------------- small kernels ----------------
__global__ void k_ones(float* imp) {
  int t = blockIdx.x * 256 + threadIdx.x;
  if (t < 2048) imp[t] = 1.0f;
}

__global__ void k_rowsum(const float* __restrict__ thp, float* __restrict__ imp) {
  int i = blockIdx.x;
  float a = 0.f;
  for (int j = threadIdx.x; j < N_NODES; j += 256) a += thp[(size_t)i * N_NODES + j];
  float s = blockSum256(a);
  if (threadIdx.x == 0) imp[i] = s;
}

__global__ void k_colsum(const float* __restrict__ thp, float* __restrict__ imp) {
  int j = blockIdx.x * 256 + threadIdx.x;
  if (j >= N_NODES) return;
  int r0 = blockIdx.y * 125;
  float a = 0.f;
  for (int i = r0; i < r0 + 125; ++i) a += thp[(size_t)i * N_NODES + j];
  atomicAdd(&imp[1024 + j], a);
}

__global__ void k_scale_b(const float* __restrict__ xs, const float* __restrict__ xt,
                          const float* __restrict__ imp, float* __restrict__ h) {
  int g = blockIdx.y, i = blockIdx.x, d = threadIdx.x;
  const float* x = g ? xt : xs;
  h[(size_t)g * 256000 + i * DIM + d] = x[i * DIM + d] * imp[g * 1024 + i];
}

__global__ void k_agg_b(const float* __restrict__ h, const int* __restrict__ start,
                        const int* __restrict__ part, float* __restrict__ agg) {
  int g = blockIdx.y, i = blockIdx.x, d = threadIdx.x;
  const int* st = start + g * 1008;
  const int* pt = part + g * 16000;
  const float* hh = h + (size_t)g * 256000;
  int e0 = st[i], e1 = st[i + 1];
  float a = 0.f;
  for (int q = e0; q < e1; ++q) a += hh[(size_t)pt[q] * DIM + d];
  agg[(size_t)g * 256000 + i * DIM + d] = a;
}

__global__ void __launch_bounds__(256) k_lin_b(const float* __restrict__ h_,
    const float* __restrict__ agg_, const float* __restrict__ Wm,
    const float* __restrict__ bias, float* __restrict__ out_, int relu) {
  __shared__ float As[16][64];
  __shared__ float Ws[64][64];
  int g = blockIdx.z;
  const float* h   = h_   + (size_t)g * 256000;
  const float* agg = agg_ + (size_t)g * 256000;
  float* out       = out_ + (size_t)g * 256000;
  int tx = threadIdx.x & 63;
  int ty = threadIdx.x >> 6;
  int row0 = blockIdx.x * 16;
  int col0 = blockIdx.y * 64;
  float acc[4] = {0.f, 0.f, 0.f, 0.f};
  for (int kc = 0; kc < DIM; kc += 64) {
    for (int t = threadIdx.x; t < 16 * 64; t += 256) {
      int r = t >> 6, c = t & 63;
      int gr = row0 + r;
      As[r][c] = (gr < N_NODES) ? (h[gr * DIM + kc + c] + agg[gr * DIM + kc + c]) : 0.f;
    }
    for (int t = threadIdx.x; t < 64 * 64; t += 256) {
      int r = t >> 6, c = t & 63;
      Ws[r][c] = Wm[(kc + r) * DIM + col0 + c];
    }
    __syncthreads();
    #pragma unroll 8
    for (int kk = 0; kk < 64; ++kk) {
      float w = Ws[kk][tx];
      acc[0] += As[ty][kk] * w;
      acc[1] += As[ty + 4][kk] * w;
      acc[2] += As[ty + 8][kk] * w;
      acc[3] += As[ty + 12][kk] * w;
    }
    __syncthreads();
  }
  int col = col0 + tx;
  float bv = bias[col];
  #pragma unroll
  for (int r = 0; r < 4; ++r) {
    int gr = row0 + ty + r * 4;
    if (gr < N_NODES) {
      float vv = acc[r] + bv;
      if (relu) vv = fmaxf(vv, 0.f);
      out[gr * DIM + col] = vv;
    }
  }
}

__global__ void k_norm_b(const float* __restrict__ h, float* __restrict__ out) {
  int g = blockIdx.y, i = blockIdx.x;
  float x = h[(size_t)g * 256000 + i * DIM + threadIdx.x];
  float ss = blockSum256(x * x);
  float nrm = sqrtf(ss);
  out[(size_t)g * 256000 + i * DIM + threadIdx.x] = x / nrm;
}

__global__ void __launch_bounds__(256) k_gemm50(const float* __restrict__ A,
    const float* __restrict__ B, float* __restrict__ C) {
  __shared__ float As[64][33];
  __shared__ float Bs[64][33];
  int tr = threadIdx.x >> 4;
  int tc = threadIdx.x & 15;
  int i0 = blockIdx.x * 64, j0 = blockIdx.y * 64;
  float acc[4][4] = {};
  for (int kc = 0; kc < DIM; kc += 32) {
    for (int t = threadIdx.x; t < 64 * 32; t += 256) {
      int r = t >> 5, c = t & 31;
      int gi = i0 + r; As[r][c] = (gi < N_NODES) ? A[gi * DIM + kc + c] : 0.f;
      int gj = j0 + r; Bs[r][c] = (gj < N_NODES) ? B[gj * DIM + kc + c] : 0.f;
    }
    __syncthreads();
    for (int kk = 0; kk < 32; ++kk) {
      float a[4], b[4];
      #pragma unroll
      for (int q = 0; q < 4; ++q) a[q] = As[tr * 4 + q][kk];
      #pragma unroll
      for (int q = 0; q < 4; ++q) b[q] = Bs[tc * 4 + q][kk];
      #pragma unroll
      for (int r = 0; r < 4; ++r)
        #pragma unroll
        for (int c = 0; c < 4; ++c) acc[r][c] += a[r] * b[c];
    }
    __syncthreads();
  }
  for (int r = 0; r < 4; ++r) {
    int gi = i0 + tr * 4 + r;
    if (gi >= N_NODES) continue;
    for (int c = 0; c < 4; ++c) {
      int gj = j0 + tc * 4 + c;
      if (gj < N_NODES) C[(size_t)gi * N_NODES + gj] = 50.0f * acc[r][c];
    }
  }
}

// build: Q = exp(b - u1) stored bf16 (row-normalized residual, in [0,1]);
// v1 col-partials from unrounded values. grid (ICB=400, NS) = 3200 blocks.
__global__ void __launch_bounds__(256) k_build(const float* __restrict__ la,
    unsigned short* __restrict__ Q, float* __restrict__ ps,
    uint32_t k0, uint32_t k1) {
  int ic = blockIdx.x, s = blockIdx.y;
  int t = threadIdx.x;
  int j0 = t * 8;
  bool act = (j0 < P);
  float acc[8] = {0.f,0.f,0.f,0.f,0.f,0.f,0.f,0.f};
  for (int r = 0; r < RPB; ++r) {
    int i = ic * RPB + r;
    float bv[8];
    float lmax = -INFINITY;
    if (act) {
      uint32_t idxbase = (uint32_t)((s * P + i) * P + j0);
      #pragma unroll
      for (int q = 0; q < 8; ++q) {
        int j = j0 + q;
        float g = gumbel_from_idx(k0, k1, idxbase + (uint32_t)q);
        float lav = (i < N_NODES && j < N_NODES) ? la[(size_t)i * N_NODES + j] : 0.0f;
        bv[q] = (lav + g) * 10.0f;
        lmax = fmaxf(lmax, bv[q]);
      }
    }
    float M = blockMax256(lmax);
    float e[8];
    float ls = 0.f;
    if (act) {
      #pragma unroll
      for (int q = 0; q < 8; ++q) { e[q] = __expf(bv[q] - M); ls += e[q]; }
    }
    float S = blockSum256(ls);
    if (act) {
      float rs = 1.0f / S;
      unsigned short q8[8];
      #pragma unroll
      for (int q = 0; q < 8; ++q) {
        float val = e[q] * rs;
        acc[q] += val;
        q8[q] = f2bf(val);
      }
      ushort4* qp = (ushort4*)(Q + ((size_t)s * P + i) * P + j0);
      qp[0] = make_ushort4(q8[0], q8[1], q8[2], q8[3]);
      qp[1] = make_ushort4(q8[4], q8[5], q8[6], q8[7]);
    }
  }
  if (act) {
    float* pp = ps + ((size_t)(s * ICB + ic)) * 2048 + j0;
    ((float4*)pp)[0] = make_float4(acc[0], acc[1], acc[2], acc[3]);
    ((float4*)pp)[1] = make_float4(acc[4], acc[5], acc[6], acc[7]);
  }
}

// fused sinkhorn pass on bf16 Q: e = Q*exp(-du_i)*ev_j (ev precomputed).
__global__ void __launch_bounds__(256) k_fused(const unsigned short* __restrict__ Q,
    const float* __restrict__ evbuf, float* __restrict__ du, float* __restrict__ ps) {
  int ic = blockIdx.x, s = blockIdx.y;
  int t = threadIdx.x;
  int lane = t & 63, wave = t >> 6;
  int j0 = t * 8;
  bool act = (j0 < P);
  __shared__ float pr[GR][4];
  __shared__ float Sr[GR];
  float ev[8];
  if (act) {
    float4 v0 = *(const float4*)(evbuf + s * P + j0);
    float4 v1 = *(const float4*)(evbuf + s * P + j0 + 4);
    ev[0] = v0.x; ev[1] = v0.y; ev[2] = v0.z; ev[3] = v0.w;
    ev[4] = v1.x; ev[5] = v1.y; ev[6] = v1.z; ev[7] = v1.w;
  }
  float acc[8] = {0.f,0.f,0.f,0.f,0.f,0.f,0.f,0.f};
  for (int g = 0; g < RPC / GR; ++g) {
    float e[GR][8];
    #pragma unroll
    for (int r = 0; r < GR; ++r) {
      int i = ic * RPC + g * GR + r;
      float edu = __expf(-du[s * P + i]);
      float ls = 0.f;
      if (act) {
        const unsigned short* qrow = Q + ((size_t)s * P + i) * P + j0;
        ushort4 a = *(const ushort4*)qrow;
        ushort4 b = *(const ushort4*)(qrow + 4);
        e[r][0] = bf2f(a.x) * edu * ev[0];
        e[r][1] = bf2f(a.y) * edu * ev[1];
        e[r][2] = bf2f(a.z) * edu * ev[2];
        e[r][3] = bf2f(a.w) * edu * ev[3];
        e[r][4] = bf2f(b.x) * edu * ev[4];
        e[r][5] = bf2f(b.y) * edu * ev[5];
        e[r][6] = bf2f(b.z) * edu * ev[6];
        e[r][7] = bf2f(b.w) * edu * ev[7];
        #pragma unroll
        for (int q = 0; q < 8; ++q) ls += e[r][q];
      }
      #pragma unroll
      for (int off = 32; off; off >>= 1) ls += __shfl_down(ls, off, 64);
      if (lane == 0) pr[r][wave] = ls;
    }
    __syncthreads();
    if (t < GR) {
      float S = (pr[t][0] + pr[t][1]) + (pr[t][2] + pr[t][3]);
      Sr[t] = S;
      du[s * P + ic * RPC + g * GR + t] += __logf(S);
    }
    __syncthreads();
    if (act) {
      #pragma unroll
      for (int r = 0; r < GR; ++r) {
        float rs = 1.0f / Sr[r];
        #pragma unroll
        for (int q = 0; q < 8; ++q) acc[q] += e[r][q] * rs;
      }
    }
  }
  if (act) {
    float* pp = ps + ((size_t)(s * IC2 + ic)) * 2048 + j0;
    ((float4*)pp)[0] = make_float4(acc[0], acc[1], acc[2], acc[3]);
    ((float4*)pp)[1] = make_float4(acc[4], acc[5], acc[6], acc[7]);
  }
}

// dv_new = dv_old + log(sum_c ps); also emit evbuf = exp(-dv_new)
template<int NCH>
__global__ void k_combineT(const float* __restrict__ ps, float* __restrict__ v,
                           float* __restrict__ evbuf) {
  int j = blockIdx.x * 256 + threadIdx.x;
  int s = blockIdx.y;
  if (j >= P) return;
  float S = 0.f;
  for (int c = 0; c < NCH; ++c) S += ps[((size_t)(s * NCH + c)) * 2048 + j];
  float nv = v[s * P + j] + __logf(S);
  v[s * P + j] = nv;
  evbuf[s * P + j] = __expf(-nv);
}

// theta[s,i,j] = Q*edu*ev -> bf16; optional fused fp32 mean -> thp
template<int DO_MEAN>
__global__ void __launch_bounds__(256) k_theta_mean(const unsigned short* __restrict__ Q,
    const float* __restrict__ du, const float* __restrict__ evbuf,
    unsigned short* __restrict__ th, float* __restrict__ thp) {
  int i = blockIdx.x, t = threadIdx.x;
  if (t >= 250) return;
  int j0 = t * 4;
  float4 acc = make_float4(0.f, 0.f, 0.f, 0.f);
  #pragma unroll
  for (int s = 0; s < NS; ++s) {
    float edu = __expf(-du[s * P + i]);
    ushort4 q4 = *(const ushort4*)(Q + ((size_t)s * P + i) * P + j0);
    float4 vv = *(const float4*)(evbuf + s * P + j0);
    float t0 = bf2f(q4.x) * edu * vv.x;
    float t1 = bf2f(q4.y) * edu * vv.y;
    float t2 = bf2f(q4.z) * edu * vv.z;
    float t3 = bf2f(q4.w) * edu * vv.w;
    *(ushort4*)(th + ((size_t)s * N_NODES + i) * N_NODES + j0) =
        make_ushort4(f2bf(t0), f2bf(t1), f2bf(t2), f2bf(t3));
    if (DO_MEAN) { acc.x += t0; acc.y += t1; acc.z += t2; acc.w += t3; }
  }
  if (DO_MEAN) {
    acc.x *= 0.125f; acc.y *= 0.125f; acc.z *= 0.125f; acc.w *= 0.125f;
    *(float4*)(thp + (size_t)i * N_NODES + j0) = acc;
  }
}

// fused reward on bf16 theta, XCD-affinity, NB=4 b-rows per block
__global__ void __launch_bounds__(256) k_reward(const unsigned short* __restrict__ th,
    const int* __restrict__ startA, const int* __restrict__ partA,
    const int* __restrict__ epackD, float* __restrict__ matched) {
  __shared__ float xrow[NB][N_NODES];
  __shared__ float yrow[NB][N_NODES];
  int s = blockIdx.x & 7, bg = blockIdx.x >> 3;
  int b0 = bg * NB;
  int t = threadIdx.x;
  if (t < 250) {
    #pragma unroll
    for (int nb = 0; nb < NB; ++nb) {
      int b = b0 + nb;
      ushort4 x4 = ((const ushort4*)(th + ((size_t)s * N_NODES + b) * N_NODES))[t];
      ((float4*)xrow[nb])[t] = make_float4(bf2f(x4.x), bf2f(x4.y), bf2f(x4.z), bf2f(x4.w));
      float4 y4 = make_float4(0.f, 0.f, 0.f, 0.f);
      int e0 = startA[b], e1 = startA[b + 1];
      for (int q = e0; q < e1; ++q) {
        ushort4 v4 = ((const ushort4*)(th + ((size_t)s * N_NODES + partA[q]) * N_NODES))[t];
        y4.x += bf2f(v4.x); y4.y += bf2f(v4.y); y4.z += bf2f(v4.z); y4.w += bf2f(v4.w);
      }
      ((float4*)yrow[nb])[t] = y4;
    }
  }
  __syncthreads();
  float acc = 0.f;
  for (int m = t; m < N_EDGES; m += 256) {
    int pk = epackD[m];
    int d = pk >> 10, c = pk & 1023;
    #pragma unroll
    for (int nb = 0; nb < NB; ++nb)
      acc += yrow[nb][d] * xrow[nb][c];
  }
  float ssum = blockSum256(acc);
  if (t == 0) atomicAdd(matched + s, ssum);
}

__global__ void k_fin0(const float* __restrict__ matched, float* __restrict__ scal) {
  if (threadIdx.x == 0) {
    float accm = 0.f;
    for (int s = 0; s < NS; ++s) {
      float m = matched[s];
      float rv = m + (-1.0f) * ((16000.0f - m) + (16000.0f - m));
      accm += rv;
    }
    scal[0] = (accm / 8.0f) / 16000.0f;
  }
}

__global__ void k_fin1(const float* __restrict__ matched, float* __restrict__ scal,
                       float* __restrict__ out) {
  if (threadIdx.x == 0) {
    float accm = 0.f;
    for (int s = 0; s < NS; ++s) {
      float m = matched[s];
      float rv = m + (-1.0f) * ((16000.0f - m) + (16000.0f - m));
      accm += rv;
    }
    float r1 = (accm / 8.0f) / 16000.0f;
    float r0 = scal[0];
    int improved = (r1 > r0) ? 1 : 0;
    scal[1] = r1;
    scal[2] = (float)improved;
    float loss = -r0 - (improved ? r1 : 0.f);
    float cnt = improved ? 2.0f : 1.0f;
    out[(size_t)P * P] = loss / cnt;
  }
}

__global__ void k_out_sel(const float* __restrict__ laA, const float* __restrict__ laB,
                          const float* __restrict__ scal, float* __restrict__ out) {
  int q = blockIdx.x * 256 + threadIdx.x;
  if (q >= P * P / 4) return;
  const float* la = (scal[2] != 0.0f) ? laB : laA;
  int row = q / (P / 4);
  int jc = (q % (P / 4)) * 4;
  float4 vv = make_float4(0.f, 0.f, 0.f, 0.f);
  if (row < N_NODES && jc < N_NODES)
    vv = *(const float4*)(la + (size_t)row * N_NODES + jc);
  *(float4*)(out + (size_t)row * P + jc) = vv;
}

// ---------------- launch ----------------
extern "C" void kernel_launch(void* const* d_in, const int* in_sizes, int n_in,
                              void* d_out, int out_size, void* d_ws, size_t ws_size,
                              hipStream_t stream) {
  (void)in_sizes; (void)n_in; (void)out_size; (void)ws_size;
  const float* x_s = (const float*)d_in[0];
  const int*   e_s = (const int*)d_in[1];
  const float* x_t = (const float*)d_in[2];
  const int*   e_t = (const int*)d_in[3];
  const float* W1  = (const float*)d_in[4];
  const float* b1  = (const float*)d_in[5];
  const float* W2  = (const float*)d_in[6];
  const float* b2  = (const float*)d_in[7];
  float* out = (float*)d_out;

  // workspace layout
  unsigned short* Qbuf  = (unsigned short*)d_ws;   // 32,000,000 bf16 (64 MB)
  unsigned short* theta = Qbuf + 32000000;         //  8,000,000 bf16 (16 MB)
  float* laA   = (float*)(theta + 8000000);        //  1,000,000 f32
  float* laB   = laA + 1000000;
  float* thp   = laB + 1000000;
  float* h0    = thp + 1000000;                    //    512,000 (2 graphs)
  float* agg   = h0 + 512000;
  float* h1    = agg + 512000;
  float* h2    = h1 + 512000;
  float* hn    = h2 + 512000;
  float* uarr  = hn + 512000;                      //     16,000 (du)
  float* varr  = uarr + 16000;                     //     16,000 (dv)
  float* evbuf = varr + 16000;                     //     16,000 (exp(-dv))
  float* ps    = evbuf + 16000;                    //  6,553,600 (ICB*NS*2048)
  float* imp   = ps + 6553600;                     //      2,048
  float* matched = imp + 2048;
  float* scal  = matched + 16;
  int* cnt    = (int*)(scal + 16);                 // 1,024
  int* cursor = cnt + 1024;                        // 1,024
  int* ids    = cursor + 1024;                     // 16,000
  int* startA = ids + 16000;                       // 1,008
  int* startB = startA + 1008;                     // 1,008
  int* partA  = startB + 1008;                     // 16,000
  int* partB  = partA + 16000;                     // 16,000
  int* epackD = partB + 16000;                     // 16,000

  const int* keys[2]  = { e_s + N_EDGES, e_t + N_EDGES };
  const int* parts[2] = { e_s,           e_t           };
  int* outs_s[2] = { startA, startB };
  int* outs_p[2] = { partA,  partB  };
  for (int r = 0; r < 2; ++r) {
    hipMemsetAsync(cnt, 0, 2048 * sizeof(int), stream);
    k_hist<<<63, 256, 0, stream>>>(keys[r], cnt);
    k_scan<<<1, 1024, 0, stream>>>(cnt, outs_s[r]);
    k_scatter<<<63, 256, 0, stream>>>(keys[r], outs_s[r], cursor, ids);
    k_partfill<<<63, 256, 0, stream>>>(ids, parts[r], outs_p[r]);
  }
  k_packD<<<4, 256, 0, stream>>>(startB, partB, epackD);

  uint32_t k0 = 0u, k1 = 42u;
  uint32_t sub[2][2];
  for (int it = 0; it < 2; ++it) {
    uint32_t nk0, nk1, s0, s1;
    tf2x32(k0, k1, 0u, 0u, &nk0, &nk1);
    tf2x32(k0, k1, 0u, 1u, &s0, &s1);
    sub[it][0] = s0; sub[it][1] = s1;
    k0 = nk0; k1 = nk1;
  }

  for (int it = 0; it < 2; ++it) {
    if (it == 0) {
      k_ones<<<8, 256, 0, stream>>>(imp);
    } else {
      k_rowsum<<<N_NODES, 256, 0, stream>>>(thp, imp);
      hipMemsetAsync(imp + 1024, 0, 1024 * sizeof(float), stream);
      k_colsum<<<dim3(4, 8), 256, 0, stream>>>(thp, imp);
    }
    k_scale_b<<<dim3(N_NODES, 2), 256, 0, stream>>>(x_s, x_t, imp, h0);
    k_agg_b<<<dim3(N_NODES, 2), 256, 0, stream>>>(h0, startA, partA, agg);
    k_lin_b<<<dim3(63, 4, 2), 256, 0, stream>>>(h0, agg, W1, b1, h1, 1);
    k_agg_b<<<dim3(N_NODES, 2), 256, 0, stream>>>(h1, startA, partA, agg);
    k_lin_b<<<dim3(63, 4, 2), 256, 0, stream>>>(h1, agg, W2, b2, h2, 0);
    k_norm_b<<<dim3(N_NODES, 2), 256, 0, stream>>>(h2, hn);
    float* la = it ? laB : laA;
    k_gemm50<<<dim3(16, 16), 256, 0, stream>>>(hn, hn + 256000, la);

    // sinkhorn on bf16 Q: du/dv potentials start at 0
    hipMemsetAsync(uarr, 0, 2 * NS * P * sizeof(float), stream);  // du + dv
    k_build<<<dim3(ICB, NS), 256, 0, stream>>>(la, Qbuf, ps,
                                               sub[it][0], sub[it][1]);
    k_combineT<ICB><<<dim3(8, NS), 256, 0, stream>>>(ps, varr, evbuf);
    for (int k = 0; k < 9; ++k) {
      k_fused<<<dim3(IC2, NS), 256, 0, stream>>>(Qbuf, evbuf, uarr, ps);
      k_combineT<IC2><<<dim3(8, NS), 256, 0, stream>>>(ps, varr, evbuf);
    }

    if (it == 0)
      k_theta_mean<1><<<N_NODES, 256, 0, stream>>>(Qbuf, uarr, evbuf, theta, thp);
    else
      k_theta_mean<0><<<N_NODES, 256, 0, stream>>>(Qbuf, uarr, evbuf, theta, thp);
    hipMemsetAsync(matched, 0, NS * 4, stream);
    k_reward<<<(N_NODES / NB) * 8, 256, 0, stream>>>(theta, startA, partA,
                                                     epackD, matched);
    if (it == 0) k_fin0<<<1, 64, 0, stream>>>(matched, scal);
    else         k_fin1<<<1, 64, 0, stream>>>(matched, scal, out);
  }
  k_out_sel<<<3907, 256, 0, stream>>>(laA, laB, scal, out);
}